// Round 8
// baseline (812.113 us; speedup 1.0000x reference)
//
#include <hip/hip_runtime.h>
#include <math.h>

#define NB 4
#define TT 16
#define NNODE 1000
#define FIN 8
#define EE 8000
#define EP 9000          // E + N self loops
#define EPAD 16384       // max padded edges (pad rows to mult of 8): <= 9000+1000*7=16000
#define HID 64
#define HEADS 4
#define NL 5
#define GG (NB*TT)       // 64 graphs
#define ROWS (GG*NNODE)  // 64000
#define HCOL (HEADS*HID) // 256
#define KGI (NNODE*HID)  // 64000
#define GOUT 192         // 3*HID
#define GIK 128          // K-slice per gi-gemm block
#define KSPLIT (KGI/GIK) // 500 partial slabs
#define GOSZ (GG*GOUT)   // 12288

// ---------------- edge prep ----------------
__global__ void k_build_edges(const int* __restrict__ eidx, int* __restrict__ src_e,
                              int* __restrict__ dst_e, int* __restrict__ deg, int* __restrict__ fill) {
    int i = blockIdx.x * blockDim.x + threadIdx.x;
    if (i < EP) {
        int s, d;
        if (i < EE) { s = eidx[i]; d = eidx[EE + i]; }
        else { s = i - EE; d = i - EE; }
        src_e[i] = s; dst_e[i] = d;
    }
    if (i < NNODE) { deg[i] = 0; fill[i] = 0; }
}

__global__ void k_csr_count(const int* __restrict__ dst_e, int* __restrict__ deg) {
    int i = blockIdx.x * blockDim.x + threadIdx.x;
    if (i < EP) atomicAdd(&deg[dst_e[i]], 1);
}

// parallel inclusive scan of PADDED degrees (pad to multiple of 8)
__global__ __launch_bounds__(256) void k_csr_scan(const int* __restrict__ deg, int* __restrict__ rowptr_p) {
    __shared__ int s[1024];
    int tid = threadIdx.x;
    for (int i = tid; i < 1024; i += 256) s[i] = (i < NNODE) ? ((deg[i] + 7) & ~7) : 0;
    __syncthreads();
    for (int off = 1; off < 1024; off <<= 1) {
        int t[4];
        #pragma unroll
        for (int q = 0; q < 4; q++) { int i = tid + 256 * q; t[q] = (i >= off) ? s[i - off] : 0; }
        __syncthreads();
        #pragma unroll
        for (int q = 0; q < 4; q++) { int i = tid + 256 * q; s[i] += t[q]; }
        __syncthreads();
    }
    for (int i = tid; i < NNODE; i += 256) rowptr_p[i + 1] = s[i];
    if (tid == 0) rowptr_p[0] = 0;
}

__global__ void k_csr_fill(const int* __restrict__ src_e, const int* __restrict__ dst_e,
                           const int* __restrict__ rowptr_p, int* __restrict__ fill,
                           int* __restrict__ csr_src) {
    int i = blockIdx.x * blockDim.x + threadIdx.x;
    if (i < EP) {
        int d = dst_e[i];
        int pos = atomicAdd(&fill[d], 1);
        csr_src[rowptr_p[d] + pos] = src_e[i];
    }
}

// fill pad slots with dummy self-edges (alpha assigns them weight 0)
__global__ void k_pad_fill(const int* __restrict__ rowptr_p, const int* __restrict__ deg,
                           int* __restrict__ csr_src) {
    int n = blockIdx.x * blockDim.x + threadIdx.x;
    if (n >= NNODE) return;
    int rs = rowptr_p[n], re = rowptr_p[n + 1];
    for (int j = rs + deg[n]; j < re; j++) csr_src[j] = n;
}

// ---------------- input projection (float4 over columns) ----------------
__global__ void k_input_fc(const float* __restrict__ xseq, const float4* __restrict__ Win4,
                           const float4* __restrict__ b_in4, float4* __restrict__ x0) {
    int idx = blockIdx.x * 256 + threadIdx.x;   // ROWS*16 threads
    int r = idx >> 4, c4 = idx & 15;
    float4 acc = b_in4[c4];
    #pragma unroll
    for (int k = 0; k < FIN; k++) {
        float xv = xseq[r * FIN + k];
        float4 w = Win4[k * 16 + c4];
        acc.x += xv * w.x; acc.y += xv * w.y; acc.z += xv * w.z; acc.w += xv * w.w;
    }
    x0[idx] = acc;
}

// ---------------- GAT: h = x @ W (64 rows x 256 cols/block, 8x8 per thread), ls/ld fused ----------------
__global__ __launch_bounds__(256) void k_gat_h(const float4* __restrict__ x4, const float4* __restrict__ W4,
                                               const float* __restrict__ asrc, const float* __restrict__ adst,
                                               float* __restrict__ h, float* __restrict__ ls, float* __restrict__ ld) {
    __shared__ float xs[64 * 68];     // [k][row], pitch 68
    __shared__ float ws[64 * 260];    // [k][col], pitch 260
    int tid = threadIdx.x;
    int a = tid & 63;
    int tx = tid & 31, ty = tid >> 5;
    int h0 = tx >> 4;                 // head of low cols; high cols head = h0+2
    // stage W once (64x256)
    for (int idx = tid; idx < 4096; idx += 256) {
        int k = idx >> 6, j = idx & 63;
        *reinterpret_cast<float4*>(&ws[k * 260 + j * 4]) = W4[(size_t)k * 64 + j];
    }
    float4 av0 = *reinterpret_cast<const float4*>(&asrc[tx * 4]);
    float4 av1 = *reinterpret_cast<const float4*>(&asrc[128 + tx * 4]);
    float4 dv0 = *reinterpret_cast<const float4*>(&adst[tx * 4]);
    float4 dv1 = *reinterpret_cast<const float4*>(&adst[128 + tx * 4]);
    int rbase = ty * 8;

    for (int t = 0; t < 4; t++) {
        int r0 = (blockIdx.x * 4 + t) * 64;
        __syncthreads();              // xs safe to overwrite; first iter: W staged
        #pragma unroll
        for (int it = 0; it < 4; it++) {
            int kq = (tid >> 6) + 4 * it;
            float4 v = x4[(size_t)(r0 + a) * 16 + kq];
            int k = kq * 4;
            xs[(k + 0) * 68 + a] = v.x;
            xs[(k + 1) * 68 + a] = v.y;
            xs[(k + 2) * 68 + a] = v.z;
            xs[(k + 3) * 68 + a] = v.w;
        }
        __syncthreads();
        float acc[8][8];
        #pragma unroll
        for (int i = 0; i < 8; i++)
            #pragma unroll
            for (int j = 0; j < 8; j++) acc[i][j] = 0.f;
        for (int k = 0; k < 64; k++) {
            float4 xv0 = *reinterpret_cast<const float4*>(&xs[k * 68 + rbase]);
            float4 xv1 = *reinterpret_cast<const float4*>(&xs[k * 68 + rbase + 4]);
            float4 w0 = *reinterpret_cast<const float4*>(&ws[k * 260 + tx * 4]);
            float4 w1 = *reinterpret_cast<const float4*>(&ws[k * 260 + 128 + tx * 4]);
            float xr[8] = {xv0.x, xv0.y, xv0.z, xv0.w, xv1.x, xv1.y, xv1.z, xv1.w};
            #pragma unroll
            for (int i = 0; i < 8; i++) {
                acc[i][0] += xr[i] * w0.x; acc[i][1] += xr[i] * w0.y;
                acc[i][2] += xr[i] * w0.z; acc[i][3] += xr[i] * w0.w;
                acc[i][4] += xr[i] * w1.x; acc[i][5] += xr[i] * w1.y;
                acc[i][6] += xr[i] * w1.z; acc[i][7] += xr[i] * w1.w;
            }
        }
        #pragma unroll
        for (int i = 0; i < 8; i++) {
            int row = r0 + rbase + i;
            *reinterpret_cast<float4*>(&h[(size_t)row * HCOL + tx * 4]) =
                make_float4(acc[i][0], acc[i][1], acc[i][2], acc[i][3]);
            *reinterpret_cast<float4*>(&h[(size_t)row * HCOL + 128 + tx * 4]) =
                make_float4(acc[i][4], acc[i][5], acc[i][6], acc[i][7]);
            float psl = acc[i][0] * av0.x + acc[i][1] * av0.y + acc[i][2] * av0.z + acc[i][3] * av0.w;
            float psh = acc[i][4] * av1.x + acc[i][5] * av1.y + acc[i][6] * av1.z + acc[i][7] * av1.w;
            float pdl = acc[i][0] * dv0.x + acc[i][1] * dv0.y + acc[i][2] * dv0.z + acc[i][3] * dv0.w;
            float pdh = acc[i][4] * dv1.x + acc[i][5] * dv1.y + acc[i][6] * dv1.z + acc[i][7] * dv1.w;
            #pragma unroll
            for (int m = 1; m < 16; m <<= 1) {
                psl += __shfl_xor(psl, m, 64);
                psh += __shfl_xor(psh, m, 64);
                pdl += __shfl_xor(pdl, m, 64);
                pdh += __shfl_xor(pdh, m, 64);
            }
            if ((tx & 15) == 0) {
                ls[(size_t)row * HEADS + h0] = psl;
                ls[(size_t)row * HEADS + h0 + 2] = psh;
                ld[(size_t)row * HEADS + h0] = pdl;
                ld[(size_t)row * HEADS + h0 + 2] = pdh;
            }
        }
    }
}

// ---------------- fused logits + softmax + alpha, per (g,n); writes PADDED alpha ----------------
__global__ __launch_bounds__(256) void k_alpha(const float4* __restrict__ ls4, const float4* __restrict__ ld4,
                                               const int* __restrict__ rowptr_p, const int* __restrict__ csr_src,
                                               const int* __restrict__ deg, float4* __restrict__ abuf) {
    int idx = blockIdx.x * 256 + threadIdx.x;     // GG*NNODE
    if (idx >= GG * NNODE) return;
    int g = idx / NNODE, n = idx - g * NNODE;
    int rs = rowptr_p[n], re = rowptr_p[n + 1];
    int dgp = re - rs;
    int dg = deg[n];
    float4 ldv = ld4[(size_t)g * NNODE + n];
    const float4* lsg = ls4 + (size_t)g * NNODE;
    float4* out = abuf + (size_t)g * EPAD;
    if (dgp == 8) {
        int sv[8]; float4 v[8];
        #pragma unroll
        for (int u = 0; u < 8; u++) sv[u] = csr_src[rs + u];
        #pragma unroll
        for (int u = 0; u < 8; u++) {
            float4 t = lsg[sv[u]];
            t.x += ldv.x; t.y += ldv.y; t.z += ldv.z; t.w += ldv.w;
            t.x = fmaxf(t.x, 0.2f * t.x); t.y = fmaxf(t.y, 0.2f * t.y);
            t.z = fmaxf(t.z, 0.2f * t.z); t.w = fmaxf(t.w, 0.2f * t.w);
            v[u] = t;
        }
        float4 m = make_float4(-1e30f, -1e30f, -1e30f, -1e30f);
        #pragma unroll
        for (int u = 0; u < 8; u++) {
            if (u < dg) {
                m.x = fmaxf(m.x, v[u].x); m.y = fmaxf(m.y, v[u].y);
                m.z = fmaxf(m.z, v[u].z); m.w = fmaxf(m.w, v[u].w);
            }
        }
        float4 den = make_float4(0.f, 0.f, 0.f, 0.f);
        #pragma unroll
        for (int u = 0; u < 8; u++) {
            if (u < dg) {
                v[u].x = expf(v[u].x - m.x); den.x += v[u].x;
                v[u].y = expf(v[u].y - m.y); den.y += v[u].y;
                v[u].z = expf(v[u].z - m.z); den.z += v[u].z;
                v[u].w = expf(v[u].w - m.w); den.w += v[u].w;
            }
        }
        float4 inv = make_float4(1.f / (den.x + 1e-16f), 1.f / (den.y + 1e-16f),
                                 1.f / (den.z + 1e-16f), 1.f / (den.w + 1e-16f));
        #pragma unroll
        for (int u = 0; u < 8; u++) {
            float4 t = (u < dg)
                ? make_float4(v[u].x * inv.x, v[u].y * inv.y, v[u].z * inv.z, v[u].w * inv.w)
                : make_float4(0.f, 0.f, 0.f, 0.f);
            out[rs + u] = t;
        }
    } else if (dgp == 16) {
        int sv[16]; float4 v[16];
        #pragma unroll
        for (int u = 0; u < 16; u++) sv[u] = csr_src[rs + u];
        #pragma unroll
        for (int u = 0; u < 16; u++) {
            float4 t = lsg[sv[u]];
            t.x += ldv.x; t.y += ldv.y; t.z += ldv.z; t.w += ldv.w;
            t.x = fmaxf(t.x, 0.2f * t.x); t.y = fmaxf(t.y, 0.2f * t.y);
            t.z = fmaxf(t.z, 0.2f * t.z); t.w = fmaxf(t.w, 0.2f * t.w);
            v[u] = t;
        }
        float4 m = make_float4(-1e30f, -1e30f, -1e30f, -1e30f);
        #pragma unroll
        for (int u = 0; u < 16; u++) {
            if (u < dg) {
                m.x = fmaxf(m.x, v[u].x); m.y = fmaxf(m.y, v[u].y);
                m.z = fmaxf(m.z, v[u].z); m.w = fmaxf(m.w, v[u].w);
            }
        }
        float4 den = make_float4(0.f, 0.f, 0.f, 0.f);
        #pragma unroll
        for (int u = 0; u < 16; u++) {
            if (u < dg) {
                v[u].x = expf(v[u].x - m.x); den.x += v[u].x;
                v[u].y = expf(v[u].y - m.y); den.y += v[u].y;
                v[u].z = expf(v[u].z - m.z); den.z += v[u].z;
                v[u].w = expf(v[u].w - m.w); den.w += v[u].w;
            }
        }
        float4 inv = make_float4(1.f / (den.x + 1e-16f), 1.f / (den.y + 1e-16f),
                                 1.f / (den.z + 1e-16f), 1.f / (den.w + 1e-16f));
        #pragma unroll
        for (int u = 0; u < 16; u++) {
            float4 t = (u < dg)
                ? make_float4(v[u].x * inv.x, v[u].y * inv.y, v[u].z * inv.z, v[u].w * inv.w)
                : make_float4(0.f, 0.f, 0.f, 0.f);
            out[rs + u] = t;
        }
    } else {
        float4 m = make_float4(-1e30f, -1e30f, -1e30f, -1e30f);
        for (int j = rs; j < rs + dg; j++) {
            float4 t = lsg[csr_src[j]];
            t.x += ldv.x; t.y += ldv.y; t.z += ldv.z; t.w += ldv.w;
            t.x = fmaxf(t.x, 0.2f * t.x); t.y = fmaxf(t.y, 0.2f * t.y);
            t.z = fmaxf(t.z, 0.2f * t.z); t.w = fmaxf(t.w, 0.2f * t.w);
            out[j] = t;
            m.x = fmaxf(m.x, t.x); m.y = fmaxf(m.y, t.y);
            m.z = fmaxf(m.z, t.z); m.w = fmaxf(m.w, t.w);
        }
        float4 den = make_float4(0.f, 0.f, 0.f, 0.f);
        for (int j = rs; j < rs + dg; j++) {
            float4 t = out[j];
            t.x = expf(t.x - m.x); den.x += t.x;
            t.y = expf(t.y - m.y); den.y += t.y;
            t.z = expf(t.z - m.z); den.z += t.z;
            t.w = expf(t.w - m.w); den.w += t.w;
            out[j] = t;
        }
        float4 inv = make_float4(1.f / (den.x + 1e-16f), 1.f / (den.y + 1e-16f),
                                 1.f / (den.z + 1e-16f), 1.f / (den.w + 1e-16f));
        for (int j = rs; j < rs + dg; j++) {
            float4 t = out[j];
            t.x *= inv.x; t.y *= inv.y; t.z *= inv.z; t.w *= inv.w;
            out[j] = t;
        }
        for (int j = rs + dg; j < re; j++) out[j] = make_float4(0.f, 0.f, 0.f, 0.f);
    }
}

// ---------------- GAT aggregate: one wave per 4 nodes, unpredicated 8-chunks, XCD swizzle ----------------
__global__ __launch_bounds__(256) void k_agg(const float4* __restrict__ h4, const float* __restrict__ alpha,
                                             const int* __restrict__ rowptr_p, const int* __restrict__ csr_src,
                                             const float4* __restrict__ bg4, float4* __restrict__ xout4) {
    int b = blockIdx.x;              // 0..3999
    int xcd = b & 7, s = b >> 3;
    int tid = threadIdx.x;
    int wid = tid >> 6, lane = tid & 63;
    int w = s * 4 + wid;             // 0..1999 per XCD
    int g = xcd + 8 * (w / 250);
    int n0 = (w % 250) * 4;
    int head = lane >> 4, c4 = lane & 15;
    const float* agg_base = alpha + (size_t)g * EPAD * HEADS + head;
    const float4* hg = h4 + (size_t)g * NNODE * 64 + lane;   // head*16+c4 == lane
    float4 bb = bg4[c4];

    #pragma unroll
    for (int nn = 0; nn < 4; nn++) {
        int n = n0 + nn;
        int rs = rowptr_p[n], re = rowptr_p[n + 1];
        float4 acc = make_float4(0.f, 0.f, 0.f, 0.f);
        for (int j0 = rs; j0 < re; j0 += 8) {
            int sv[8]; float av[8];
            const float* agc = agg_base + (size_t)j0 * HEADS;
            const int* sp = csr_src + j0;
            #pragma unroll
            for (int u = 0; u < 8; u++) {
                sv[u] = sp[u];
                av[u] = agc[u * HEADS];
            }
            float4 hv[8];
            #pragma unroll
            for (int u = 0; u < 8; u++) hv[u] = hg[(size_t)sv[u] * 64];
            #pragma unroll
            for (int u = 0; u < 8; u++) {
                acc.x += av[u] * hv[u].x;
                acc.y += av[u] * hv[u].y;
                acc.z += av[u] * hv[u].z;
                acc.w += av[u] * hv[u].w;
            }
        }
        #pragma unroll
        for (int m = 16; m < 64; m <<= 1) {
            acc.x += __shfl_xor(acc.x, m, 64);
            acc.y += __shfl_xor(acc.y, m, 64);
            acc.z += __shfl_xor(acc.z, m, 64);
            acc.w += __shfl_xor(acc.w, m, 64);
        }
        if (head == 0) {
            float4 r;
            r.x = acc.x * 0.25f + bb.x;
            r.y = acc.y * 0.25f + bb.y;
            r.z = acc.z * 0.25f + bb.z;
            r.w = acc.w * 0.25f + bb.w;
            r.x = r.x > 0.f ? r.x : expm1f(r.x);
            r.y = r.y > 0.f ? r.y : expm1f(r.y);
            r.z = r.z > 0.f ? r.z : expm1f(r.z);
            r.w = r.w > 0.f ? r.w : expm1f(r.w);
            xout4[((size_t)g * NNODE + n) * 16 + c4] = r;
        }
    }
}

// ---------------- GRU input GEMM: 500 K-slices, full 64x192 tile/block, no atomics ----------------
__global__ __launch_bounds__(256) void k_gi_gemm(const float* __restrict__ x, const float* __restrict__ W_ih,
                                                 float* __restrict__ gip) {
    __shared__ float xs[32 * 68];    // [kk][row], pitch 68
    __shared__ float ws[32 * 196];   // [kk][col 0..191], pitch 196
    int k0 = blockIdx.x * GIK;
    int tid = threadIdx.x;
    int lane = tid & 63;
    int wv = tid >> 6;
    int tx = tid & 15, ty = tid >> 4;
    float4 accs[4][3];
    #pragma unroll
    for (int i = 0; i < 4; i++)
        #pragma unroll
        for (int j = 0; j < 3; j++) accs[i][j] = make_float4(0.f, 0.f, 0.f, 0.f);

    for (int kt = 0; kt < GIK / 32; kt++) {
        int kb = k0 + kt * 32;
        #pragma unroll
        for (int it = 0; it < 2; it++) {
            int kq = wv + 4 * it;
            float4 v = *reinterpret_cast<const float4*>(&x[(size_t)lane * KGI + kb + kq * 4]);
            int k = kq * 4;
            xs[(k + 0) * 68 + lane] = v.x;
            xs[(k + 1) * 68 + lane] = v.y;
            xs[(k + 2) * 68 + lane] = v.z;
            xs[(k + 3) * 68 + lane] = v.w;
        }
        #pragma unroll
        for (int cg = 0; cg < 3; cg++) {
            #pragma unroll
            for (int it = 0; it < 2; it++) {
                int kq = wv + 4 * it;
                int c = cg * 64 + lane;
                float4 v = *reinterpret_cast<const float4*>(&W_ih[(size_t)c * KGI + kb + kq * 4]);
                int k = kq * 4;
                ws[(k + 0) * 196 + c] = v.x;
                ws[(k + 1) * 196 + c] = v.y;
                ws[(k + 2) * 196 + c] = v.z;
                ws[(k + 3) * 196 + c] = v.w;
            }
        }
        __syncthreads();
        for (int kk = 0; kk < 32; kk++) {
            float4 xv = *reinterpret_cast<const float4*>(&xs[kk * 68 + ty * 4]);
            float4 w0 = *reinterpret_cast<const float4*>(&ws[kk * 196 + tx * 4]);
            float4 w1 = *reinterpret_cast<const float4*>(&ws[kk * 196 + 64 + tx * 4]);
            float4 w2 = *reinterpret_cast<const float4*>(&ws[kk * 196 + 128 + tx * 4]);
            #pragma unroll
            for (int i = 0; i < 4; i++) {
                float xi = (i == 0) ? xv.x : (i == 1) ? xv.y : (i == 2) ? xv.z : xv.w;
                accs[i][0].x += xi * w0.x; accs[i][0].y += xi * w0.y; accs[i][0].z += xi * w0.z; accs[i][0].w += xi * w0.w;
                accs[i][1].x += xi * w1.x; accs[i][1].y += xi * w1.y; accs[i][1].z += xi * w1.z; accs[i][1].w += xi * w1.w;
                accs[i][2].x += xi * w2.x; accs[i][2].y += xi * w2.y; accs[i][2].z += xi * w2.z; accs[i][2].w += xi * w2.w;
            }
        }
        __syncthreads();
    }
    float* out = gip + (size_t)blockIdx.x * GOSZ;
    #pragma unroll
    for (int i = 0; i < 4; i++)
        #pragma unroll
        for (int j = 0; j < 3; j++)
            *reinterpret_cast<float4*>(&out[(ty * 4 + i) * GOUT + j * 64 + tx * 4]) = accs[i][j];
}

__global__ void k_gi_reduce1(const float* __restrict__ gip, float* __restrict__ gip2) {
    int idx = blockIdx.x * 256 + threadIdx.x;     // 0..GOSZ-1
    const float* p = gip + (size_t)blockIdx.y * 50 * GOSZ + idx;
    float a = 0.f;
    #pragma unroll 5
    for (int s = 0; s < 50; s++) a += p[(size_t)s * GOSZ];
    gip2[blockIdx.y * GOSZ + idx] = a;
}

__global__ void k_gi_reduce2(const float* __restrict__ gip2, const float* __restrict__ b_ih,
                             float* __restrict__ gi) {
    int idx = blockIdx.x * 256 + threadIdx.x;
    float a = b_ih[idx % GOUT];
    #pragma unroll
    for (int y = 0; y < 10; y++) a += gip2[(size_t)y * GOSZ + idx];
    gi[idx] = a;
}

// ---------------- GRU scan (single block) ----------------
__global__ __launch_bounds__(256) void k_gru(const float* __restrict__ gi, const float* __restrict__ W_hh,
                                             const float* __restrict__ b_hh, float* __restrict__ hT) {
    __shared__ float Wt[64 * 192];   // [c][j] transposed
    __shared__ float hs[4][64];
    __shared__ float gh[4][192];
    int tid = threadIdx.x;
    for (int idx = tid; idx < 192 * 64; idx += 256) {
        int j = idx >> 6, c = idx & 63;
        Wt[c * 192 + j] = W_hh[idx];
    }
    int b_ = tid >> 6, c_ = tid & 63;
    hs[b_][c_] = 0.f;
    __syncthreads();
    for (int t = 0; t < TT; t++) {
        #pragma unroll
        for (int q = 0; q < 3; q++) {
            int p = tid + 256 * q;
            int bb = p / GOUT, j = p % GOUT;
            float a = b_hh[j];
            for (int c = 0; c < 64; c++) a += hs[bb][c] * Wt[c * 192 + j];
            gh[bb][j] = a;
        }
        __syncthreads();
        int row = (b_ * TT + t) * GOUT;
        float ir = gi[row + c_], iz = gi[row + 64 + c_], in_ = gi[row + 128 + c_];
        float r = 1.f / (1.f + expf(-(ir + gh[b_][c_])));
        float z = 1.f / (1.f + expf(-(iz + gh[b_][64 + c_])));
        float nv = tanhf(in_ + r * gh[b_][128 + c_]);
        float hn = (1.f - z) * nv + z * hs[b_][c_];
        hs[b_][c_] = hn;
        __syncthreads();
    }
    hT[tid] = hs[b_][c_];
}

// ---------------- final FC ----------------
__global__ void k_final(const float* __restrict__ hT, const float* __restrict__ W_fc,
                        const float* __restrict__ b_fc, float* __restrict__ out) {
    int idx = blockIdx.x * 256 + threadIdx.x;
    if (idx >= NB * NNODE) return;
    int b = idx / NNODE, n = idx % NNODE;
    float acc = b_fc[n];
    #pragma unroll
    for (int c = 0; c < HID; c++) acc += hT[b * HID + c] * W_fc[c * NNODE + n];
    out[idx] = acc;
}

extern "C" void kernel_launch(void* const* d_in, const int* in_sizes, int n_in,
                              void* d_out, int out_size, void* d_ws, size_t ws_size,
                              hipStream_t stream) {
    const float* x_seq  = (const float*)d_in[0];
    const int*   eidx   = (const int*)  d_in[1];
    // d_in[2] edge_weight: unused by GATConv
    const float* W_in   = (const float*)d_in[3];
    const float* b_in   = (const float*)d_in[4];
    const float* Wg     = (const float*)d_in[5];
    const float* a_src  = (const float*)d_in[6];
    const float* a_dst  = (const float*)d_in[7];
    const float* bg     = (const float*)d_in[8];
    const float* W_ih   = (const float*)d_in[9];
    const float* W_hh   = (const float*)d_in[10];
    const float* b_ih   = (const float*)d_in[11];
    const float* b_hh   = (const float*)d_in[12];
    const float* W_fc   = (const float*)d_in[13];
    const float* b_fc   = (const float*)d_in[14];
    float* out = (float*)d_out;

    float* wsf = (float*)d_ws;
    size_t off = 0;
    float* x0     = wsf + off; off += (size_t)ROWS * HID;       // 4,096,000
    float* hbuf   = wsf + off; off += (size_t)ROWS * HCOL;      // 16,384,000
    float* lsb    = wsf + off; off += (size_t)ROWS * HEADS;     // 256,000
    float* ldb    = wsf + off; off += (size_t)ROWS * HEADS;     // 256,000
    float* abuf   = wsf + off; off += (size_t)GG * EPAD * HEADS;// 4,194,304
    float* gib    = wsf + off; off += GOSZ;                     // 12,288
    float* hTb    = wsf + off; off += 256;
    int* ib = (int*)(wsf + off);
    int* src_e    = ib;          ib += EP;
    int* dst_e    = ib;          ib += EP;
    int* rowptr_p = ib;          ib += NNODE + 1;
    int* csr_src  = ib;          ib += EPAD;
    int* deg      = ib;          ib += NNODE;
    int* fill     = ib;          ib += NNODE;

    // gi partials alias hbuf (dead after last k_agg): (500+10)*12288 floats << 16.38M
    float* gip  = hbuf;
    float* gip2 = hbuf + (size_t)KSPLIT * GOSZ;

    k_build_edges<<<(EP + 255) / 256, 256, 0, stream>>>(eidx, src_e, dst_e, deg, fill);
    k_csr_count<<<(EP + 255) / 256, 256, 0, stream>>>(dst_e, deg);
    k_csr_scan<<<1, 256, 0, stream>>>(deg, rowptr_p);
    k_csr_fill<<<(EP + 255) / 256, 256, 0, stream>>>(src_e, dst_e, rowptr_p, fill, csr_src);
    k_pad_fill<<<(NNODE + 255) / 256, 256, 0, stream>>>(rowptr_p, deg, csr_src);

    k_input_fc<<<ROWS * 16 / 256, 256, 0, stream>>>(x_seq, (const float4*)W_in, (const float4*)b_in,
                                                    (float4*)x0);

    for (int l = 0; l < NL; l++) {
        k_gat_h<<<250, 256, 0, stream>>>(
            (const float4*)x0, (const float4*)(Wg + (size_t)l * HID * HCOL),
            a_src + (size_t)l * HEADS * HID, a_dst + (size_t)l * HEADS * HID, hbuf, lsb, ldb);
        k_alpha<<<(GG * NNODE + 255) / 256, 256, 0, stream>>>(
            (const float4*)lsb, (const float4*)ldb, rowptr_p, csr_src, deg, (float4*)abuf);
        k_agg<<<ROWS / 16, 256, 0, stream>>>(
            (const float4*)hbuf, abuf, rowptr_p, csr_src,
            (const float4*)(bg + (size_t)l * HID), (float4*)x0);
    }

    k_gi_gemm<<<KSPLIT, 256, 0, stream>>>(x0, W_ih, gip);
    k_gi_reduce1<<<dim3(GOSZ / 256, 10), 256, 0, stream>>>(gip, gip2);
    k_gi_reduce2<<<GOSZ / 256, 256, 0, stream>>>(gip2, b_ih, gib);
    k_gru<<<1, 256, 0, stream>>>(gib, W_hh, b_hh, hTb);
    k_final<<<(NB * NNODE + 255) / 256, 256, 0, stream>>>(hTb, W_fc, b_fc, out);
}

// Round 9
// 775.003 us; speedup vs baseline: 1.0479x; 1.0479x over previous
//
#include <hip/hip_runtime.h>
#include <math.h>

#define NB 4
#define TT 16
#define NNODE 1000
#define FIN 8
#define EE 8000
#define EP 9000          // E + N self loops
#define EPAD 16384       // max padded edges (pad rows to mult of 8): <= 9000+1000*7=16000
#define HID 64
#define HEADS 4
#define NL 5
#define GG (NB*TT)       // 64 graphs
#define ROWS (GG*NNODE)  // 64000
#define HCOL (HEADS*HID) // 256
#define KGI (NNODE*HID)  // 64000
#define GOUT 192         // 3*HID
#define GIK 128          // K-slice per gi-gemm block
#define KSPLIT (KGI/GIK) // 500 partial slabs
#define GOSZ (GG*GOUT)   // 12288

// ---------------- edge prep ----------------
__global__ void k_build_edges(const int* __restrict__ eidx, int* __restrict__ src_e,
                              int* __restrict__ dst_e, int* __restrict__ deg, int* __restrict__ fill) {
    int i = blockIdx.x * blockDim.x + threadIdx.x;
    if (i < EP) {
        int s, d;
        if (i < EE) { s = eidx[i]; d = eidx[EE + i]; }
        else { s = i - EE; d = i - EE; }
        src_e[i] = s; dst_e[i] = d;
    }
    if (i < NNODE) { deg[i] = 0; fill[i] = 0; }
}

__global__ void k_csr_count(const int* __restrict__ dst_e, int* __restrict__ deg) {
    int i = blockIdx.x * blockDim.x + threadIdx.x;
    if (i < EP) atomicAdd(&deg[dst_e[i]], 1);
}

// parallel inclusive scan of PADDED degrees (pad to multiple of 8)
__global__ __launch_bounds__(256) void k_csr_scan(const int* __restrict__ deg, int* __restrict__ rowptr_p) {
    __shared__ int s[1024];
    int tid = threadIdx.x;
    for (int i = tid; i < 1024; i += 256) s[i] = (i < NNODE) ? ((deg[i] + 7) & ~7) : 0;
    __syncthreads();
    for (int off = 1; off < 1024; off <<= 1) {
        int t[4];
        #pragma unroll
        for (int q = 0; q < 4; q++) { int i = tid + 256 * q; t[q] = (i >= off) ? s[i - off] : 0; }
        __syncthreads();
        #pragma unroll
        for (int q = 0; q < 4; q++) { int i = tid + 256 * q; s[i] += t[q]; }
        __syncthreads();
    }
    for (int i = tid; i < NNODE; i += 256) rowptr_p[i + 1] = s[i];
    if (tid == 0) rowptr_p[0] = 0;
}

__global__ void k_csr_fill(const int* __restrict__ src_e, const int* __restrict__ dst_e,
                           const int* __restrict__ rowptr_p, int* __restrict__ fill,
                           int* __restrict__ csr_src) {
    int i = blockIdx.x * blockDim.x + threadIdx.x;
    if (i < EP) {
        int d = dst_e[i];
        int pos = atomicAdd(&fill[d], 1);
        csr_src[rowptr_p[d] + pos] = src_e[i];
    }
}

// fill pad slots with dummy self-edges (alpha assigns them weight 0)
__global__ void k_pad_fill(const int* __restrict__ rowptr_p, const int* __restrict__ deg,
                           int* __restrict__ csr_src) {
    int n = blockIdx.x * blockDim.x + threadIdx.x;
    if (n >= NNODE) return;
    int rs = rowptr_p[n], re = rowptr_p[n + 1];
    for (int j = rs + deg[n]; j < re; j++) csr_src[j] = n;
}

// ---------------- input projection (float4 over columns) ----------------
__global__ void k_input_fc(const float* __restrict__ xseq, const float4* __restrict__ Win4,
                           const float4* __restrict__ b_in4, float4* __restrict__ x0) {
    int idx = blockIdx.x * 256 + threadIdx.x;   // ROWS*16 threads
    int r = idx >> 4, c4 = idx & 15;
    float4 acc = b_in4[c4];
    #pragma unroll
    for (int k = 0; k < FIN; k++) {
        float xv = xseq[r * FIN + k];
        float4 w = Win4[k * 16 + c4];
        acc.x += xv * w.x; acc.y += xv * w.y; acc.z += xv * w.z; acc.w += xv * w.w;
    }
    x0[idx] = acc;
}

// ---------------- GAT: h = x @ W. 128 rows x 128 cols (2 heads) per block, 8x8/thread.
// x staged in LDS (34 KB); W read per-k via global (L1/L2-resident, VMEM pipe). ls/ld fused.
__global__ __launch_bounds__(256) void k_gat_h(const float4* __restrict__ x4, const float* __restrict__ W,
                                               const float* __restrict__ asrc, const float* __restrict__ adst,
                                               float* __restrict__ h, float* __restrict__ ls, float* __restrict__ ld) {
    __shared__ float xs[64 * 132];    // [k][row], pitch 132
    int tid = threadIdx.x;
    int r0 = blockIdx.x * 128;
    int hb = blockIdx.y;              // 0..1 -> heads 2*hb, 2*hb+1
    int c0 = hb * 128;
    int rg = tid >> 4;                // 0..15, 8 rows each
    int cg = tid & 15;                // 0..15, 8 cols each
    // stage x transposed: row = tid&127 (lane-consecutive -> 2-way bank = free)
    {
        int row = tid & 127;
        int kq0 = tid >> 7;           // 0..1
        #pragma unroll
        for (int it = 0; it < 8; it++) {
            int kq = kq0 + 2 * it;    // 0..15
            float4 v = x4[(size_t)(r0 + row) * 16 + kq];
            int k = kq * 4;
            xs[(k + 0) * 132 + row] = v.x;
            xs[(k + 1) * 132 + row] = v.y;
            xs[(k + 2) * 132 + row] = v.z;
            xs[(k + 3) * 132 + row] = v.w;
        }
    }
    __syncthreads();
    const float* wp = W + c0 + cg * 8;
    float acc[8][8];
    #pragma unroll
    for (int i = 0; i < 8; i++)
        #pragma unroll
        for (int j = 0; j < 8; j++) acc[i][j] = 0.f;
    #pragma unroll 4
    for (int k = 0; k < 64; k++) {
        float4 w0 = *reinterpret_cast<const float4*>(&wp[(size_t)k * HCOL]);
        float4 w1 = *reinterpret_cast<const float4*>(&wp[(size_t)k * HCOL + 4]);
        float4 xv0 = *reinterpret_cast<const float4*>(&xs[k * 132 + rg * 8]);
        float4 xv1 = *reinterpret_cast<const float4*>(&xs[k * 132 + rg * 8 + 4]);
        float xr[8] = {xv0.x, xv0.y, xv0.z, xv0.w, xv1.x, xv1.y, xv1.z, xv1.w};
        #pragma unroll
        for (int i = 0; i < 8; i++) {
            acc[i][0] += xr[i] * w0.x; acc[i][1] += xr[i] * w0.y;
            acc[i][2] += xr[i] * w0.z; acc[i][3] += xr[i] * w0.w;
            acc[i][4] += xr[i] * w1.x; acc[i][5] += xr[i] * w1.y;
            acc[i][6] += xr[i] * w1.z; acc[i][7] += xr[i] * w1.w;
        }
    }
    int head = 2 * hb + (cg >> 3);
    int ccg = cg & 7;
    float4 av0 = *reinterpret_cast<const float4*>(&asrc[head * 64 + ccg * 8]);
    float4 av1 = *reinterpret_cast<const float4*>(&asrc[head * 64 + ccg * 8 + 4]);
    float4 dv0 = *reinterpret_cast<const float4*>(&adst[head * 64 + ccg * 8]);
    float4 dv1 = *reinterpret_cast<const float4*>(&adst[head * 64 + ccg * 8 + 4]);
    #pragma unroll
    for (int i = 0; i < 8; i++) {
        int row = r0 + rg * 8 + i;
        *reinterpret_cast<float4*>(&h[(size_t)row * HCOL + c0 + cg * 8]) =
            make_float4(acc[i][0], acc[i][1], acc[i][2], acc[i][3]);
        *reinterpret_cast<float4*>(&h[(size_t)row * HCOL + c0 + cg * 8 + 4]) =
            make_float4(acc[i][4], acc[i][5], acc[i][6], acc[i][7]);
        float ps = acc[i][0] * av0.x + acc[i][1] * av0.y + acc[i][2] * av0.z + acc[i][3] * av0.w
                 + acc[i][4] * av1.x + acc[i][5] * av1.y + acc[i][6] * av1.z + acc[i][7] * av1.w;
        float pd = acc[i][0] * dv0.x + acc[i][1] * dv0.y + acc[i][2] * dv0.z + acc[i][3] * dv0.w
                 + acc[i][4] * dv1.x + acc[i][5] * dv1.y + acc[i][6] * dv1.z + acc[i][7] * dv1.w;
        #pragma unroll
        for (int m = 1; m < 8; m <<= 1) {
            ps += __shfl_xor(ps, m, 64);
            pd += __shfl_xor(pd, m, 64);
        }
        if (ccg == 0) {
            ls[(size_t)row * HEADS + head] = ps;
            ld[(size_t)row * HEADS + head] = pd;
        }
    }
}

// ---------------- fused logits + softmax + alpha, per (g,n); writes PADDED alpha ----------------
__global__ __launch_bounds__(256) void k_alpha(const float4* __restrict__ ls4, const float4* __restrict__ ld4,
                                               const int* __restrict__ rowptr_p, const int* __restrict__ csr_src,
                                               const int* __restrict__ deg, float4* __restrict__ abuf) {
    int idx = blockIdx.x * 256 + threadIdx.x;     // GG*NNODE
    if (idx >= GG * NNODE) return;
    int g = idx / NNODE, n = idx - g * NNODE;
    int rs = rowptr_p[n], re = rowptr_p[n + 1];
    int dgp = re - rs;
    int dg = deg[n];
    float4 ldv = ld4[(size_t)g * NNODE + n];
    const float4* lsg = ls4 + (size_t)g * NNODE;
    float4* out = abuf + (size_t)g * EPAD;
    if (dgp == 8) {
        int sv[8]; float4 v[8];
        #pragma unroll
        for (int u = 0; u < 8; u++) sv[u] = csr_src[rs + u];
        #pragma unroll
        for (int u = 0; u < 8; u++) {
            float4 t = lsg[sv[u]];
            t.x += ldv.x; t.y += ldv.y; t.z += ldv.z; t.w += ldv.w;
            t.x = fmaxf(t.x, 0.2f * t.x); t.y = fmaxf(t.y, 0.2f * t.y);
            t.z = fmaxf(t.z, 0.2f * t.z); t.w = fmaxf(t.w, 0.2f * t.w);
            v[u] = t;
        }
        float4 m = make_float4(-1e30f, -1e30f, -1e30f, -1e30f);
        #pragma unroll
        for (int u = 0; u < 8; u++) {
            if (u < dg) {
                m.x = fmaxf(m.x, v[u].x); m.y = fmaxf(m.y, v[u].y);
                m.z = fmaxf(m.z, v[u].z); m.w = fmaxf(m.w, v[u].w);
            }
        }
        float4 den = make_float4(0.f, 0.f, 0.f, 0.f);
        #pragma unroll
        for (int u = 0; u < 8; u++) {
            if (u < dg) {
                v[u].x = expf(v[u].x - m.x); den.x += v[u].x;
                v[u].y = expf(v[u].y - m.y); den.y += v[u].y;
                v[u].z = expf(v[u].z - m.z); den.z += v[u].z;
                v[u].w = expf(v[u].w - m.w); den.w += v[u].w;
            }
        }
        float4 inv = make_float4(1.f / (den.x + 1e-16f), 1.f / (den.y + 1e-16f),
                                 1.f / (den.z + 1e-16f), 1.f / (den.w + 1e-16f));
        #pragma unroll
        for (int u = 0; u < 8; u++) {
            float4 t = (u < dg)
                ? make_float4(v[u].x * inv.x, v[u].y * inv.y, v[u].z * inv.z, v[u].w * inv.w)
                : make_float4(0.f, 0.f, 0.f, 0.f);
            out[rs + u] = t;
        }
    } else if (dgp == 16) {
        int sv[16]; float4 v[16];
        #pragma unroll
        for (int u = 0; u < 16; u++) sv[u] = csr_src[rs + u];
        #pragma unroll
        for (int u = 0; u < 16; u++) {
            float4 t = lsg[sv[u]];
            t.x += ldv.x; t.y += ldv.y; t.z += ldv.z; t.w += ldv.w;
            t.x = fmaxf(t.x, 0.2f * t.x); t.y = fmaxf(t.y, 0.2f * t.y);
            t.z = fmaxf(t.z, 0.2f * t.z); t.w = fmaxf(t.w, 0.2f * t.w);
            v[u] = t;
        }
        float4 m = make_float4(-1e30f, -1e30f, -1e30f, -1e30f);
        #pragma unroll
        for (int u = 0; u < 16; u++) {
            if (u < dg) {
                m.x = fmaxf(m.x, v[u].x); m.y = fmaxf(m.y, v[u].y);
                m.z = fmaxf(m.z, v[u].z); m.w = fmaxf(m.w, v[u].w);
            }
        }
        float4 den = make_float4(0.f, 0.f, 0.f, 0.f);
        #pragma unroll
        for (int u = 0; u < 16; u++) {
            if (u < dg) {
                v[u].x = expf(v[u].x - m.x); den.x += v[u].x;
                v[u].y = expf(v[u].y - m.y); den.y += v[u].y;
                v[u].z = expf(v[u].z - m.z); den.z += v[u].z;
                v[u].w = expf(v[u].w - m.w); den.w += v[u].w;
            }
        }
        float4 inv = make_float4(1.f / (den.x + 1e-16f), 1.f / (den.y + 1e-16f),
                                 1.f / (den.z + 1e-16f), 1.f / (den.w + 1e-16f));
        #pragma unroll
        for (int u = 0; u < 16; u++) {
            float4 t = (u < dg)
                ? make_float4(v[u].x * inv.x, v[u].y * inv.y, v[u].z * inv.z, v[u].w * inv.w)
                : make_float4(0.f, 0.f, 0.f, 0.f);
            out[rs + u] = t;
        }
    } else {
        float4 m = make_float4(-1e30f, -1e30f, -1e30f, -1e30f);
        for (int j = rs; j < rs + dg; j++) {
            float4 t = lsg[csr_src[j]];
            t.x += ldv.x; t.y += ldv.y; t.z += ldv.z; t.w += ldv.w;
            t.x = fmaxf(t.x, 0.2f * t.x); t.y = fmaxf(t.y, 0.2f * t.y);
            t.z = fmaxf(t.z, 0.2f * t.z); t.w = fmaxf(t.w, 0.2f * t.w);
            out[j] = t;
            m.x = fmaxf(m.x, t.x); m.y = fmaxf(m.y, t.y);
            m.z = fmaxf(m.z, t.z); m.w = fmaxf(m.w, t.w);
        }
        float4 den = make_float4(0.f, 0.f, 0.f, 0.f);
        for (int j = rs; j < rs + dg; j++) {
            float4 t = out[j];
            t.x = expf(t.x - m.x); den.x += t.x;
            t.y = expf(t.y - m.y); den.y += t.y;
            t.z = expf(t.z - m.z); den.z += t.z;
            t.w = expf(t.w - m.w); den.w += t.w;
            out[j] = t;
        }
        float4 inv = make_float4(1.f / (den.x + 1e-16f), 1.f / (den.y + 1e-16f),
                                 1.f / (den.z + 1e-16f), 1.f / (den.w + 1e-16f));
        for (int j = rs; j < rs + dg; j++) {
            float4 t = out[j];
            t.x *= inv.x; t.y *= inv.y; t.z *= inv.z; t.w *= inv.w;
            out[j] = t;
        }
        for (int j = rs + dg; j < re; j++) out[j] = make_float4(0.f, 0.f, 0.f, 0.f);
    }
}

// ---------------- GAT aggregate: one wave per 4 nodes, unpredicated 8-chunks, XCD swizzle ----------------
__global__ __launch_bounds__(256) void k_agg(const float4* __restrict__ h4, const float* __restrict__ alpha,
                                             const int* __restrict__ rowptr_p, const int* __restrict__ csr_src,
                                             const float4* __restrict__ bg4, float4* __restrict__ xout4) {
    int b = blockIdx.x;              // 0..3999
    int xcd = b & 7, s = b >> 3;
    int tid = threadIdx.x;
    int wid = tid >> 6, lane = tid & 63;
    int w = s * 4 + wid;             // 0..1999 per XCD
    int g = xcd + 8 * (w / 250);
    int n0 = (w % 250) * 4;
    int head = lane >> 4, c4 = lane & 15;
    const float* agg_base = alpha + (size_t)g * EPAD * HEADS + head;
    const float4* hg = h4 + (size_t)g * NNODE * 64 + lane;   // head*16+c4 == lane
    float4 bb = bg4[c4];

    #pragma unroll
    for (int nn = 0; nn < 4; nn++) {
        int n = n0 + nn;
        int rs = rowptr_p[n], re = rowptr_p[n + 1];
        float4 acc = make_float4(0.f, 0.f, 0.f, 0.f);
        for (int j0 = rs; j0 < re; j0 += 8) {
            int sv[8]; float av[8];
            const float* agc = agg_base + (size_t)j0 * HEADS;
            const int* sp = csr_src + j0;
            #pragma unroll
            for (int u = 0; u < 8; u++) {
                sv[u] = sp[u];
                av[u] = agc[u * HEADS];
            }
            float4 hv[8];
            #pragma unroll
            for (int u = 0; u < 8; u++) hv[u] = hg[(size_t)sv[u] * 64];
            #pragma unroll
            for (int u = 0; u < 8; u++) {
                acc.x += av[u] * hv[u].x;
                acc.y += av[u] * hv[u].y;
                acc.z += av[u] * hv[u].z;
                acc.w += av[u] * hv[u].w;
            }
        }
        #pragma unroll
        for (int m = 16; m < 64; m <<= 1) {
            acc.x += __shfl_xor(acc.x, m, 64);
            acc.y += __shfl_xor(acc.y, m, 64);
            acc.z += __shfl_xor(acc.z, m, 64);
            acc.w += __shfl_xor(acc.w, m, 64);
        }
        if (head == 0) {
            float4 r;
            r.x = acc.x * 0.25f + bb.x;
            r.y = acc.y * 0.25f + bb.y;
            r.z = acc.z * 0.25f + bb.z;
            r.w = acc.w * 0.25f + bb.w;
            r.x = r.x > 0.f ? r.x : expm1f(r.x);
            r.y = r.y > 0.f ? r.y : expm1f(r.y);
            r.z = r.z > 0.f ? r.z : expm1f(r.z);
            r.w = r.w > 0.f ? r.w : expm1f(r.w);
            xout4[((size_t)g * NNODE + n) * 16 + c4] = r;
        }
    }
}

// ---------------- GRU input GEMM: 500 K-slices, full 64x192 tile/block, no atomics ----------------
__global__ __launch_bounds__(256) void k_gi_gemm(const float* __restrict__ x, const float* __restrict__ W_ih,
                                                 float* __restrict__ gip) {
    __shared__ float xs[32 * 68];    // [kk][row], pitch 68
    __shared__ float ws[32 * 196];   // [kk][col 0..191], pitch 196
    int k0 = blockIdx.x * GIK;
    int tid = threadIdx.x;
    int lane = tid & 63;
    int wv = tid >> 6;
    int tx = tid & 15, ty = tid >> 4;
    float4 accs[4][3];
    #pragma unroll
    for (int i = 0; i < 4; i++)
        #pragma unroll
        for (int j = 0; j < 3; j++) accs[i][j] = make_float4(0.f, 0.f, 0.f, 0.f);

    for (int kt = 0; kt < GIK / 32; kt++) {
        int kb = k0 + kt * 32;
        #pragma unroll
        for (int it = 0; it < 2; it++) {
            int kq = wv + 4 * it;
            float4 v = *reinterpret_cast<const float4*>(&x[(size_t)lane * KGI + kb + kq * 4]);
            int k = kq * 4;
            xs[(k + 0) * 68 + lane] = v.x;
            xs[(k + 1) * 68 + lane] = v.y;
            xs[(k + 2) * 68 + lane] = v.z;
            xs[(k + 3) * 68 + lane] = v.w;
        }
        #pragma unroll
        for (int cg = 0; cg < 3; cg++) {
            #pragma unroll
            for (int it = 0; it < 2; it++) {
                int kq = wv + 4 * it;
                int c = cg * 64 + lane;
                float4 v = *reinterpret_cast<const float4*>(&W_ih[(size_t)c * KGI + kb + kq * 4]);
                int k = kq * 4;
                ws[(k + 0) * 196 + c] = v.x;
                ws[(k + 1) * 196 + c] = v.y;
                ws[(k + 2) * 196 + c] = v.z;
                ws[(k + 3) * 196 + c] = v.w;
            }
        }
        __syncthreads();
        for (int kk = 0; kk < 32; kk++) {
            float4 xv = *reinterpret_cast<const float4*>(&xs[kk * 68 + ty * 4]);
            float4 w0 = *reinterpret_cast<const float4*>(&ws[kk * 196 + tx * 4]);
            float4 w1 = *reinterpret_cast<const float4*>(&ws[kk * 196 + 64 + tx * 4]);
            float4 w2 = *reinterpret_cast<const float4*>(&ws[kk * 196 + 128 + tx * 4]);
            #pragma unroll
            for (int i = 0; i < 4; i++) {
                float xi = (i == 0) ? xv.x : (i == 1) ? xv.y : (i == 2) ? xv.z : xv.w;
                accs[i][0].x += xi * w0.x; accs[i][0].y += xi * w0.y; accs[i][0].z += xi * w0.z; accs[i][0].w += xi * w0.w;
                accs[i][1].x += xi * w1.x; accs[i][1].y += xi * w1.y; accs[i][1].z += xi * w1.z; accs[i][1].w += xi * w1.w;
                accs[i][2].x += xi * w2.x; accs[i][2].y += xi * w2.y; accs[i][2].z += xi * w2.z; accs[i][2].w += xi * w2.w;
            }
        }
        __syncthreads();
    }
    float* out = gip + (size_t)blockIdx.x * GOSZ;
    #pragma unroll
    for (int i = 0; i < 4; i++)
        #pragma unroll
        for (int j = 0; j < 3; j++)
            *reinterpret_cast<float4*>(&out[(ty * 4 + i) * GOUT + j * 64 + tx * 4]) = accs[i][j];
}

__global__ void k_gi_reduce1(const float* __restrict__ gip, float* __restrict__ gip2) {
    int idx = blockIdx.x * 256 + threadIdx.x;     // 0..GOSZ-1
    const float* p = gip + (size_t)blockIdx.y * 50 * GOSZ + idx;
    float a = 0.f;
    #pragma unroll 5
    for (int s = 0; s < 50; s++) a += p[(size_t)s * GOSZ];
    gip2[blockIdx.y * GOSZ + idx] = a;
}

__global__ void k_gi_reduce2(const float* __restrict__ gip2, const float* __restrict__ b_ih,
                             float* __restrict__ gi) {
    int idx = blockIdx.x * 256 + threadIdx.x;
    float a = b_ih[idx % GOUT];
    #pragma unroll
    for (int y = 0; y < 10; y++) a += gip2[(size_t)y * GOSZ + idx];
    gi[idx] = a;
}

// ---------------- GRU scan (single block) ----------------
__global__ __launch_bounds__(256) void k_gru(const float* __restrict__ gi, const float* __restrict__ W_hh,
                                             const float* __restrict__ b_hh, float* __restrict__ hT) {
    __shared__ float Wt[64 * 192];   // [c][j] transposed
    __shared__ float hs[4][64];
    __shared__ float gh[4][192];
    int tid = threadIdx.x;
    for (int idx = tid; idx < 192 * 64; idx += 256) {
        int j = idx >> 6, c = idx & 63;
        Wt[c * 192 + j] = W_hh[idx];
    }
    int b_ = tid >> 6, c_ = tid & 63;
    hs[b_][c_] = 0.f;
    __syncthreads();
    for (int t = 0; t < TT; t++) {
        #pragma unroll
        for (int q = 0; q < 3; q++) {
            int p = tid + 256 * q;
            int bb = p / GOUT, j = p % GOUT;
            float a = b_hh[j];
            for (int c = 0; c < 64; c++) a += hs[bb][c] * Wt[c * 192 + j];
            gh[bb][j] = a;
        }
        __syncthreads();
        int row = (b_ * TT + t) * GOUT;
        float ir = gi[row + c_], iz = gi[row + 64 + c_], in_ = gi[row + 128 + c_];
        float r = 1.f / (1.f + expf(-(ir + gh[b_][c_])));
        float z = 1.f / (1.f + expf(-(iz + gh[b_][64 + c_])));
        float nv = tanhf(in_ + r * gh[b_][128 + c_]);
        float hn = (1.f - z) * nv + z * hs[b_][c_];
        hs[b_][c_] = hn;
        __syncthreads();
    }
    hT[tid] = hs[b_][c_];
}

// ---------------- final FC ----------------
__global__ void k_final(const float* __restrict__ hT, const float* __restrict__ W_fc,
                        const float* __restrict__ b_fc, float* __restrict__ out) {
    int idx = blockIdx.x * 256 + threadIdx.x;
    if (idx >= NB * NNODE) return;
    int b = idx / NNODE, n = idx % NNODE;
    float acc = b_fc[n];
    #pragma unroll
    for (int c = 0; c < HID; c++) acc += hT[b * HID + c] * W_fc[c * NNODE + n];
    out[idx] = acc;
}

extern "C" void kernel_launch(void* const* d_in, const int* in_sizes, int n_in,
                              void* d_out, int out_size, void* d_ws, size_t ws_size,
                              hipStream_t stream) {
    const float* x_seq  = (const float*)d_in[0];
    const int*   eidx   = (const int*)  d_in[1];
    // d_in[2] edge_weight: unused by GATConv
    const float* W_in   = (const float*)d_in[3];
    const float* b_in   = (const float*)d_in[4];
    const float* Wg     = (const float*)d_in[5];
    const float* a_src  = (const float*)d_in[6];
    const float* a_dst  = (const float*)d_in[7];
    const float* bg     = (const float*)d_in[8];
    const float* W_ih   = (const float*)d_in[9];
    const float* W_hh   = (const float*)d_in[10];
    const float* b_ih   = (const float*)d_in[11];
    const float* b_hh   = (const float*)d_in[12];
    const float* W_fc   = (const float*)d_in[13];
    const float* b_fc   = (const float*)d_in[14];
    float* out = (float*)d_out;

    float* wsf = (float*)d_ws;
    size_t off = 0;
    float* x0     = wsf + off; off += (size_t)ROWS * HID;       // 4,096,000
    float* hbuf   = wsf + off; off += (size_t)ROWS * HCOL;      // 16,384,000
    float* lsb    = wsf + off; off += (size_t)ROWS * HEADS;     // 256,000
    float* ldb    = wsf + off; off += (size_t)ROWS * HEADS;     // 256,000
    float* abuf   = wsf + off; off += (size_t)GG * EPAD * HEADS;// 4,194,304
    float* gib    = wsf + off; off += GOSZ;                     // 12,288
    float* hTb    = wsf + off; off += 256;
    int* ib = (int*)(wsf + off);
    int* src_e    = ib;          ib += EP;
    int* dst_e    = ib;          ib += EP;
    int* rowptr_p = ib;          ib += NNODE + 1;
    int* csr_src  = ib;          ib += EPAD;
    int* deg      = ib;          ib += NNODE;
    int* fill     = ib;          ib += NNODE;

    // gi partials alias hbuf (dead after last k_agg): (500+10)*12288 floats << 16.38M
    float* gip  = hbuf;
    float* gip2 = hbuf + (size_t)KSPLIT * GOSZ;

    k_build_edges<<<(EP + 255) / 256, 256, 0, stream>>>(eidx, src_e, dst_e, deg, fill);
    k_csr_count<<<(EP + 255) / 256, 256, 0, stream>>>(dst_e, deg);
    k_csr_scan<<<1, 256, 0, stream>>>(deg, rowptr_p);
    k_csr_fill<<<(EP + 255) / 256, 256, 0, stream>>>(src_e, dst_e, rowptr_p, fill, csr_src);
    k_pad_fill<<<(NNODE + 255) / 256, 256, 0, stream>>>(rowptr_p, deg, csr_src);

    k_input_fc<<<ROWS * 16 / 256, 256, 0, stream>>>(x_seq, (const float4*)W_in, (const float4*)b_in,
                                                    (float4*)x0);

    for (int l = 0; l < NL; l++) {
        k_gat_h<<<dim3(ROWS / 128, 2), 256, 0, stream>>>(
            (const float4*)x0, Wg + (size_t)l * HID * HCOL,
            a_src + (size_t)l * HEADS * HID, a_dst + (size_t)l * HEADS * HID, hbuf, lsb, ldb);
        k_alpha<<<(GG * NNODE + 255) / 256, 256, 0, stream>>>(
            (const float4*)lsb, (const float4*)ldb, rowptr_p, csr_src, deg, (float4*)abuf);
        k_agg<<<ROWS / 16, 256, 0, stream>>>(
            (const float4*)hbuf, abuf, rowptr_p, csr_src,
            (const float4*)(bg + (size_t)l * HID), (float4*)x0);
    }

    k_gi_gemm<<<KSPLIT, 256, 0, stream>>>(x0, W_ih, gip);
    k_gi_reduce1<<<dim3(GOSZ / 256, 10), 256, 0, stream>>>(gip, gip2);
    k_gi_reduce2<<<GOSZ / 256, 256, 0, stream>>>(gip2, b_ih, gib);
    k_gru<<<1, 256, 0, stream>>>(gib, W_hh, b_hh, hTb);
    k_final<<<(NB * NNODE + 255) / 256, 256, 0, stream>>>(hTb, W_fc, b_fc, out);
}

// Round 10
// 699.607 us; speedup vs baseline: 1.1608x; 1.1078x over previous
//
#include <hip/hip_runtime.h>
#include <math.h>

#define NB 4
#define TT 16
#define NNODE 1000
#define FIN 8
#define EE 8000
#define EP 9000          // E + N self loops
#define EPAD 16384       // max padded edges (pad rows to mult of 8)
#define HID 64
#define HEADS 4
#define NL 5
#define GG (NB*TT)       // 64 graphs
#define ROWS (GG*NNODE)  // 64000
#define HCOL (HEADS*HID) // 256
#define KGI (NNODE*HID)  // 64000
#define GOUT 192         // 3*HID
#define GIK 128          // K-slice per gi-gemm block
#define KSPLIT (KGI/GIK) // 500 partial slabs
#define GOSZ (GG*GOUT)   // 12288

// ---------------- edge prep ----------------
__global__ void k_build_edges(const int* __restrict__ eidx, int* __restrict__ src_e,
                              int* __restrict__ dst_e, int* __restrict__ deg, int* __restrict__ fill) {
    int i = blockIdx.x * blockDim.x + threadIdx.x;
    if (i < EP) {
        int s, d;
        if (i < EE) { s = eidx[i]; d = eidx[EE + i]; }
        else { s = i - EE; d = i - EE; }
        src_e[i] = s; dst_e[i] = d;
    }
    if (i < NNODE) { deg[i] = 0; fill[i] = 0; }
}

__global__ void k_csr_count(const int* __restrict__ dst_e, int* __restrict__ deg) {
    int i = blockIdx.x * blockDim.x + threadIdx.x;
    if (i < EP) atomicAdd(&deg[dst_e[i]], 1);
}

// parallel inclusive scan of PADDED degrees (pad to multiple of 8)
__global__ __launch_bounds__(256) void k_csr_scan(const int* __restrict__ deg, int* __restrict__ rowptr_p) {
    __shared__ int s[1024];
    int tid = threadIdx.x;
    for (int i = tid; i < 1024; i += 256) s[i] = (i < NNODE) ? ((deg[i] + 7) & ~7) : 0;
    __syncthreads();
    for (int off = 1; off < 1024; off <<= 1) {
        int t[4];
        #pragma unroll
        for (int q = 0; q < 4; q++) { int i = tid + 256 * q; t[q] = (i >= off) ? s[i - off] : 0; }
        __syncthreads();
        #pragma unroll
        for (int q = 0; q < 4; q++) { int i = tid + 256 * q; s[i] += t[q]; }
        __syncthreads();
    }
    for (int i = tid; i < NNODE; i += 256) rowptr_p[i + 1] = s[i];
    if (tid == 0) rowptr_p[0] = 0;
}

__global__ void k_csr_fill(const int* __restrict__ src_e, const int* __restrict__ dst_e,
                           const int* __restrict__ rowptr_p, int* __restrict__ fill,
                           int* __restrict__ csr_src) {
    int i = blockIdx.x * blockDim.x + threadIdx.x;
    if (i < EP) {
        int d = dst_e[i];
        int pos = atomicAdd(&fill[d], 1);
        csr_src[rowptr_p[d] + pos] = src_e[i];
    }
}

// fill pad slots with dummy self-edges (they get alpha = 0 in the fused agg)
__global__ void k_pad_fill(const int* __restrict__ rowptr_p, const int* __restrict__ deg,
                           int* __restrict__ csr_src) {
    int n = blockIdx.x * blockDim.x + threadIdx.x;
    if (n >= NNODE) return;
    int rs = rowptr_p[n], re = rowptr_p[n + 1];
    for (int j = rs + deg[n]; j < re; j++) csr_src[j] = n;
}

// ---------------- input projection (float4 over columns) ----------------
__global__ void k_input_fc(const float* __restrict__ xseq, const float4* __restrict__ Win4,
                           const float4* __restrict__ b_in4, float4* __restrict__ x0) {
    int idx = blockIdx.x * 256 + threadIdx.x;   // ROWS*16 threads
    int r = idx >> 4, c4 = idx & 15;
    float4 acc = b_in4[c4];
    #pragma unroll
    for (int k = 0; k < FIN; k++) {
        float xv = xseq[r * FIN + k];
        float4 w = Win4[k * 16 + c4];
        acc.x += xv * w.x; acc.y += xv * w.y; acc.z += xv * w.z; acc.w += xv * w.w;
    }
    x0[idx] = acc;
}

// ---------------- GAT: h = x @ W. 128 rows x 128 cols (2 heads) per block, 8x8/thread.
// x staged in LDS (34 KB); W read per-k via global (L1/L2-resident). ls/ld fused.
__global__ __launch_bounds__(256) void k_gat_h(const float4* __restrict__ x4, const float* __restrict__ W,
                                               const float* __restrict__ asrc, const float* __restrict__ adst,
                                               float* __restrict__ h, float* __restrict__ ls, float* __restrict__ ld) {
    __shared__ float xs[64 * 132];    // [k][row], pitch 132
    int tid = threadIdx.x;
    int r0 = blockIdx.x * 128;
    int hb = blockIdx.y;              // 0..1 -> heads 2*hb, 2*hb+1
    int c0 = hb * 128;
    int rg = tid >> 4;                // 0..15, 8 rows each
    int cg = tid & 15;                // 0..15, 8 cols each
    {
        int row = tid & 127;
        int kq0 = tid >> 7;           // 0..1
        #pragma unroll
        for (int it = 0; it < 8; it++) {
            int kq = kq0 + 2 * it;    // 0..15
            float4 v = x4[(size_t)(r0 + row) * 16 + kq];
            int k = kq * 4;
            xs[(k + 0) * 132 + row] = v.x;
            xs[(k + 1) * 132 + row] = v.y;
            xs[(k + 2) * 132 + row] = v.z;
            xs[(k + 3) * 132 + row] = v.w;
        }
    }
    __syncthreads();
    const float* wp = W + c0 + cg * 8;
    float acc[8][8];
    #pragma unroll
    for (int i = 0; i < 8; i++)
        #pragma unroll
        for (int j = 0; j < 8; j++) acc[i][j] = 0.f;
    #pragma unroll 4
    for (int k = 0; k < 64; k++) {
        float4 w0 = *reinterpret_cast<const float4*>(&wp[(size_t)k * HCOL]);
        float4 w1 = *reinterpret_cast<const float4*>(&wp[(size_t)k * HCOL + 4]);
        float4 xv0 = *reinterpret_cast<const float4*>(&xs[k * 132 + rg * 8]);
        float4 xv1 = *reinterpret_cast<const float4*>(&xs[k * 132 + rg * 8 + 4]);
        float xr[8] = {xv0.x, xv0.y, xv0.z, xv0.w, xv1.x, xv1.y, xv1.z, xv1.w};
        #pragma unroll
        for (int i = 0; i < 8; i++) {
            acc[i][0] += xr[i] * w0.x; acc[i][1] += xr[i] * w0.y;
            acc[i][2] += xr[i] * w0.z; acc[i][3] += xr[i] * w0.w;
            acc[i][4] += xr[i] * w1.x; acc[i][5] += xr[i] * w1.y;
            acc[i][6] += xr[i] * w1.z; acc[i][7] += xr[i] * w1.w;
        }
    }
    int head = 2 * hb + (cg >> 3);
    int ccg = cg & 7;
    float4 av0 = *reinterpret_cast<const float4*>(&asrc[head * 64 + ccg * 8]);
    float4 av1 = *reinterpret_cast<const float4*>(&asrc[head * 64 + ccg * 8 + 4]);
    float4 dv0 = *reinterpret_cast<const float4*>(&adst[head * 64 + ccg * 8]);
    float4 dv1 = *reinterpret_cast<const float4*>(&adst[head * 64 + ccg * 8 + 4]);
    #pragma unroll
    for (int i = 0; i < 8; i++) {
        int row = r0 + rg * 8 + i;
        *reinterpret_cast<float4*>(&h[(size_t)row * HCOL + c0 + cg * 8]) =
            make_float4(acc[i][0], acc[i][1], acc[i][2], acc[i][3]);
        *reinterpret_cast<float4*>(&h[(size_t)row * HCOL + c0 + cg * 8 + 4]) =
            make_float4(acc[i][4], acc[i][5], acc[i][6], acc[i][7]);
        float ps = acc[i][0] * av0.x + acc[i][1] * av0.y + acc[i][2] * av0.z + acc[i][3] * av0.w
                 + acc[i][4] * av1.x + acc[i][5] * av1.y + acc[i][6] * av1.z + acc[i][7] * av1.w;
        float pd = acc[i][0] * dv0.x + acc[i][1] * dv0.y + acc[i][2] * dv0.z + acc[i][3] * dv0.w
                 + acc[i][4] * dv1.x + acc[i][5] * dv1.y + acc[i][6] * dv1.z + acc[i][7] * dv1.w;
        #pragma unroll
        for (int m = 1; m < 8; m <<= 1) {
            ps += __shfl_xor(ps, m, 64);
            pd += __shfl_xor(pd, m, 64);
        }
        if (ccg == 0) {
            ls[(size_t)row * HEADS + head] = ps;
            ld[(size_t)row * HEADS + head] = pd;
        }
    }
}

// ---------------- fused softmax + aggregate: one wave per (g,n) ----------------
__global__ __launch_bounds__(256) void k_agg(const float4* __restrict__ h4, const float4* __restrict__ ls4,
                                             const float4* __restrict__ ld4, const int* __restrict__ rowptr_p,
                                             const int* __restrict__ csr_src, const int* __restrict__ deg,
                                             const float4* __restrict__ bg4, float4* __restrict__ xout4) {
    __shared__ float s_alpha[4][4][128];   // [wave][head][edge]
    __shared__ int   s_src[4][128];        // [wave][edge]
    int b = blockIdx.x;                    // 0..15999
    int xcd = b & 7, s = b >> 3;           // XCD round-robin; per XCD graphs sequential
    int tid = threadIdx.x;
    int wid = tid >> 6, lane = tid & 63;
    int w = s * 4 + wid;                   // 0..7999 per XCD
    int g = xcd + 8 * (w / 1000);
    int n = w - 1000 * (w / 1000);
    int rs = rowptr_p[n];
    int dgp = rowptr_p[n + 1] - rs;
    int dg = deg[n];
    float4 ldv = ld4[(size_t)g * NNODE + n];
    const float4* lsg = ls4 + (size_t)g * NNODE;

    // --- softmax phase: lane = edge ---
    int sv = 0;
    if (lane < dgp) sv = csr_src[rs + lane];
    float4 lo = make_float4(-1e30f, -1e30f, -1e30f, -1e30f);
    if (lane < dg) {
        float4 t = lsg[sv];
        t.x += ldv.x; t.y += ldv.y; t.z += ldv.z; t.w += ldv.w;
        t.x = fmaxf(t.x, 0.2f * t.x); t.y = fmaxf(t.y, 0.2f * t.y);
        t.z = fmaxf(t.z, 0.2f * t.z); t.w = fmaxf(t.w, 0.2f * t.w);
        lo = t;
    }
    int sv2 = 0;
    float4 lo2 = make_float4(-1e30f, -1e30f, -1e30f, -1e30f);
    if (dgp > 64) {                        // rare safety path (deg up to 128)
        int j2 = lane + 64;
        if (j2 < dgp) sv2 = csr_src[rs + j2];
        if (j2 < dg) {
            float4 t = lsg[sv2];
            t.x += ldv.x; t.y += ldv.y; t.z += ldv.z; t.w += ldv.w;
            t.x = fmaxf(t.x, 0.2f * t.x); t.y = fmaxf(t.y, 0.2f * t.y);
            t.z = fmaxf(t.z, 0.2f * t.z); t.w = fmaxf(t.w, 0.2f * t.w);
            lo2 = t;
        }
    }
    float4 m;
    m.x = fmaxf(lo.x, lo2.x); m.y = fmaxf(lo.y, lo2.y);
    m.z = fmaxf(lo.z, lo2.z); m.w = fmaxf(lo.w, lo2.w);
    #pragma unroll
    for (int o = 1; o < 64; o <<= 1) {
        m.x = fmaxf(m.x, __shfl_xor(m.x, o, 64));
        m.y = fmaxf(m.y, __shfl_xor(m.y, o, 64));
        m.z = fmaxf(m.z, __shfl_xor(m.z, o, 64));
        m.w = fmaxf(m.w, __shfl_xor(m.w, o, 64));
    }
    float4 e = make_float4(0.f, 0.f, 0.f, 0.f);
    if (lane < dg) {
        e.x = expf(lo.x - m.x); e.y = expf(lo.y - m.y);
        e.z = expf(lo.z - m.z); e.w = expf(lo.w - m.w);
    }
    float4 e2 = make_float4(0.f, 0.f, 0.f, 0.f);
    if (dgp > 64 && lane + 64 < dg) {
        e2.x = expf(lo2.x - m.x); e2.y = expf(lo2.y - m.y);
        e2.z = expf(lo2.z - m.z); e2.w = expf(lo2.w - m.w);
    }
    float4 den;
    den.x = e.x + e2.x; den.y = e.y + e2.y; den.z = e.z + e2.z; den.w = e.w + e2.w;
    #pragma unroll
    for (int o = 1; o < 64; o <<= 1) {
        den.x += __shfl_xor(den.x, o, 64);
        den.y += __shfl_xor(den.y, o, 64);
        den.z += __shfl_xor(den.z, o, 64);
        den.w += __shfl_xor(den.w, o, 64);
    }
    float4 inv = make_float4(1.f / (den.x + 1e-16f), 1.f / (den.y + 1e-16f),
                             1.f / (den.z + 1e-16f), 1.f / (den.w + 1e-16f));
    s_src[wid][lane] = sv;
    s_alpha[wid][0][lane] = e.x * inv.x;
    s_alpha[wid][1][lane] = e.y * inv.y;
    s_alpha[wid][2][lane] = e.z * inv.z;
    s_alpha[wid][3][lane] = e.w * inv.w;
    if (dgp > 64) {
        s_src[wid][lane + 64] = sv2;
        s_alpha[wid][0][lane + 64] = e2.x * inv.x;
        s_alpha[wid][1][lane + 64] = e2.y * inv.y;
        s_alpha[wid][2][lane + 64] = e2.z * inv.z;
        s_alpha[wid][3][lane + 64] = e2.w * inv.w;
    }
    // wave-private LDS: no barrier needed (compiler inserts lgkmcnt wait)

    // --- gather phase: lane = head*16 + c4 ---
    int head = lane >> 4, c4 = lane & 15;
    const float* ap = &s_alpha[wid][head][0];
    const int* sp = &s_src[wid][0];
    const float4* hg = h4 + (size_t)g * NNODE * 64 + lane;
    float4 acc = make_float4(0.f, 0.f, 0.f, 0.f);
    int dg16 = (dgp + 15) & ~15;
    if (dg16 > 128) dg16 = 128;
    for (int j0 = 0; j0 < dg16; j0 += 16) {
        int sj[16]; float av[16];
        #pragma unroll
        for (int u = 0; u < 16; u++) {
            sj[u] = sp[j0 + u];
            av[u] = ap[j0 + u];
        }
        float4 hv[16];
        #pragma unroll
        for (int u = 0; u < 16; u++) hv[u] = hg[(size_t)sj[u] * 64];
        #pragma unroll
        for (int u = 0; u < 16; u++) {
            acc.x += av[u] * hv[u].x;
            acc.y += av[u] * hv[u].y;
            acc.z += av[u] * hv[u].z;
            acc.w += av[u] * hv[u].w;
        }
    }
    #pragma unroll
    for (int o = 16; o < 64; o <<= 1) {
        acc.x += __shfl_xor(acc.x, o, 64);
        acc.y += __shfl_xor(acc.y, o, 64);
        acc.z += __shfl_xor(acc.z, o, 64);
        acc.w += __shfl_xor(acc.w, o, 64);
    }
    if (head == 0) {
        float4 bb = bg4[c4];
        float4 r;
        r.x = acc.x * 0.25f + bb.x;
        r.y = acc.y * 0.25f + bb.y;
        r.z = acc.z * 0.25f + bb.z;
        r.w = acc.w * 0.25f + bb.w;
        r.x = r.x > 0.f ? r.x : expm1f(r.x);
        r.y = r.y > 0.f ? r.y : expm1f(r.y);
        r.z = r.z > 0.f ? r.z : expm1f(r.z);
        r.w = r.w > 0.f ? r.w : expm1f(r.w);
        xout4[((size_t)g * NNODE + n) * 16 + c4] = r;
    }
}

// ---------------- GRU input GEMM: 500 K-slices, full 64x192 tile/block, no atomics ----------------
__global__ __launch_bounds__(256) void k_gi_gemm(const float* __restrict__ x, const float* __restrict__ W_ih,
                                                 float* __restrict__ gip) {
    __shared__ float xs[32 * 68];    // [kk][row], pitch 68
    __shared__ float ws[32 * 196];   // [kk][col 0..191], pitch 196
    int k0 = blockIdx.x * GIK;
    int tid = threadIdx.x;
    int lane = tid & 63;
    int wv = tid >> 6;
    int tx = tid & 15, ty = tid >> 4;
    float4 accs[4][3];
    #pragma unroll
    for (int i = 0; i < 4; i++)
        #pragma unroll
        for (int j = 0; j < 3; j++) accs[i][j] = make_float4(0.f, 0.f, 0.f, 0.f);

    for (int kt = 0; kt < GIK / 32; kt++) {
        int kb = k0 + kt * 32;
        #pragma unroll
        for (int it = 0; it < 2; it++) {
            int kq = wv + 4 * it;
            float4 v = *reinterpret_cast<const float4*>(&x[(size_t)lane * KGI + kb + kq * 4]);
            int k = kq * 4;
            xs[(k + 0) * 68 + lane] = v.x;
            xs[(k + 1) * 68 + lane] = v.y;
            xs[(k + 2) * 68 + lane] = v.z;
            xs[(k + 3) * 68 + lane] = v.w;
        }
        #pragma unroll
        for (int cg = 0; cg < 3; cg++) {
            #pragma unroll
            for (int it = 0; it < 2; it++) {
                int kq = wv + 4 * it;
                int c = cg * 64 + lane;
                float4 v = *reinterpret_cast<const float4*>(&W_ih[(size_t)c * KGI + kb + kq * 4]);
                int k = kq * 4;
                ws[(k + 0) * 196 + c] = v.x;
                ws[(k + 1) * 196 + c] = v.y;
                ws[(k + 2) * 196 + c] = v.z;
                ws[(k + 3) * 196 + c] = v.w;
            }
        }
        __syncthreads();
        for (int kk = 0; kk < 32; kk++) {
            float4 xv = *reinterpret_cast<const float4*>(&xs[kk * 68 + ty * 4]);
            float4 w0 = *reinterpret_cast<const float4*>(&ws[kk * 196 + tx * 4]);
            float4 w1 = *reinterpret_cast<const float4*>(&ws[kk * 196 + 64 + tx * 4]);
            float4 w2 = *reinterpret_cast<const float4*>(&ws[kk * 196 + 128 + tx * 4]);
            #pragma unroll
            for (int i = 0; i < 4; i++) {
                float xi = (i == 0) ? xv.x : (i == 1) ? xv.y : (i == 2) ? xv.z : xv.w;
                accs[i][0].x += xi * w0.x; accs[i][0].y += xi * w0.y; accs[i][0].z += xi * w0.z; accs[i][0].w += xi * w0.w;
                accs[i][1].x += xi * w1.x; accs[i][1].y += xi * w1.y; accs[i][1].z += xi * w1.z; accs[i][1].w += xi * w1.w;
                accs[i][2].x += xi * w2.x; accs[i][2].y += xi * w2.y; accs[i][2].z += xi * w2.z; accs[i][2].w += xi * w2.w;
            }
        }
        __syncthreads();
    }
    float* out = gip + (size_t)blockIdx.x * GOSZ;
    #pragma unroll
    for (int i = 0; i < 4; i++)
        #pragma unroll
        for (int j = 0; j < 3; j++)
            *reinterpret_cast<float4*>(&out[(ty * 4 + i) * GOUT + j * 64 + tx * 4]) = accs[i][j];
}

__global__ void k_gi_reduce1(const float* __restrict__ gip, float* __restrict__ gip2) {
    int idx = blockIdx.x * 256 + threadIdx.x;     // 0..GOSZ-1
    const float* p = gip + (size_t)blockIdx.y * 50 * GOSZ + idx;
    float a = 0.f;
    #pragma unroll 5
    for (int s = 0; s < 50; s++) a += p[(size_t)s * GOSZ];
    gip2[blockIdx.y * GOSZ + idx] = a;
}

__global__ void k_gi_reduce2(const float* __restrict__ gip2, const float* __restrict__ b_ih,
                             float* __restrict__ gi) {
    int idx = blockIdx.x * 256 + threadIdx.x;
    float a = b_ih[idx % GOUT];
    #pragma unroll
    for (int y = 0; y < 10; y++) a += gip2[(size_t)y * GOSZ + idx];
    gi[idx] = a;
}

// ---------------- GRU scan (single block) ----------------
__global__ __launch_bounds__(256) void k_gru(const float* __restrict__ gi, const float* __restrict__ W_hh,
                                             const float* __restrict__ b_hh, float* __restrict__ hT) {
    __shared__ float Wt[64 * 192];   // [c][j] transposed
    __shared__ float hs[4][64];
    __shared__ float gh[4][192];
    int tid = threadIdx.x;
    for (int idx = tid; idx < 192 * 64; idx += 256) {
        int j = idx >> 6, c = idx & 63;
        Wt[c * 192 + j] = W_hh[idx];
    }
    int b_ = tid >> 6, c_ = tid & 63;
    hs[b_][c_] = 0.f;
    __syncthreads();
    for (int t = 0; t < TT; t++) {
        #pragma unroll
        for (int q = 0; q < 3; q++) {
            int p = tid + 256 * q;
            int bb = p / GOUT, j = p % GOUT;
            float a = b_hh[j];
            for (int c = 0; c < 64; c++) a += hs[bb][c] * Wt[c * 192 + j];
            gh[bb][j] = a;
        }
        __syncthreads();
        int row = (b_ * TT + t) * GOUT;
        float ir = gi[row + c_], iz = gi[row + 64 + c_], in_ = gi[row + 128 + c_];
        float r = 1.f / (1.f + expf(-(ir + gh[b_][c_])));
        float z = 1.f / (1.f + expf(-(iz + gh[b_][64 + c_])));
        float nv = tanhf(in_ + r * gh[b_][128 + c_]);
        float hn = (1.f - z) * nv + z * hs[b_][c_];
        hs[b_][c_] = hn;
        __syncthreads();
    }
    hT[tid] = hs[b_][c_];
}

// ---------------- final FC ----------------
__global__ void k_final(const float* __restrict__ hT, const float* __restrict__ W_fc,
                        const float* __restrict__ b_fc, float* __restrict__ out) {
    int idx = blockIdx.x * 256 + threadIdx.x;
    if (idx >= NB * NNODE) return;
    int b = idx / NNODE, n = idx % NNODE;
    float acc = b_fc[n];
    #pragma unroll
    for (int c = 0; c < HID; c++) acc += hT[b * HID + c] * W_fc[c * NNODE + n];
    out[idx] = acc;
}

extern "C" void kernel_launch(void* const* d_in, const int* in_sizes, int n_in,
                              void* d_out, int out_size, void* d_ws, size_t ws_size,
                              hipStream_t stream) {
    const float* x_seq  = (const float*)d_in[0];
    const int*   eidx   = (const int*)  d_in[1];
    // d_in[2] edge_weight: unused by GATConv
    const float* W_in   = (const float*)d_in[3];
    const float* b_in   = (const float*)d_in[4];
    const float* Wg     = (const float*)d_in[5];
    const float* a_src  = (const float*)d_in[6];
    const float* a_dst  = (const float*)d_in[7];
    const float* bg     = (const float*)d_in[8];
    const float* W_ih   = (const float*)d_in[9];
    const float* W_hh   = (const float*)d_in[10];
    const float* b_ih   = (const float*)d_in[11];
    const float* b_hh   = (const float*)d_in[12];
    const float* W_fc   = (const float*)d_in[13];
    const float* b_fc   = (const float*)d_in[14];
    float* out = (float*)d_out;

    float* wsf = (float*)d_ws;
    size_t off = 0;
    float* x0     = wsf + off; off += (size_t)ROWS * HID;       // 4,096,000
    float* hbuf   = wsf + off; off += (size_t)ROWS * HCOL;      // 16,384,000
    float* lsb    = wsf + off; off += (size_t)ROWS * HEADS;     // 256,000
    float* ldb    = wsf + off; off += (size_t)ROWS * HEADS;     // 256,000
    float* gib    = wsf + off; off += GOSZ;                     // 12,288
    float* hTb    = wsf + off; off += 256;
    int* ib = (int*)(wsf + off);
    int* src_e    = ib;          ib += EP;
    int* dst_e    = ib;          ib += EP;
    int* rowptr_p = ib;          ib += NNODE + 1;
    int* csr_src  = ib;          ib += EPAD;
    int* deg      = ib;          ib += NNODE;
    int* fill     = ib;          ib += NNODE;

    // gi partials alias hbuf (dead after last k_agg): (500+10)*12288 floats << 16.38M
    float* gip  = hbuf;
    float* gip2 = hbuf + (size_t)KSPLIT * GOSZ;

    k_build_edges<<<(EP + 255) / 256, 256, 0, stream>>>(eidx, src_e, dst_e, deg, fill);
    k_csr_count<<<(EP + 255) / 256, 256, 0, stream>>>(dst_e, deg);
    k_csr_scan<<<1, 256, 0, stream>>>(deg, rowptr_p);
    k_csr_fill<<<(EP + 255) / 256, 256, 0, stream>>>(src_e, dst_e, rowptr_p, fill, csr_src);
    k_pad_fill<<<(NNODE + 255) / 256, 256, 0, stream>>>(rowptr_p, deg, csr_src);

    k_input_fc<<<ROWS * 16 / 256, 256, 0, stream>>>(x_seq, (const float4*)W_in, (const float4*)b_in,
                                                    (float4*)x0);

    for (int l = 0; l < NL; l++) {
        k_gat_h<<<dim3(ROWS / 128, 2), 256, 0, stream>>>(
            (const float4*)x0, Wg + (size_t)l * HID * HCOL,
            a_src + (size_t)l * HEADS * HID, a_dst + (size_t)l * HEADS * HID, hbuf, lsb, ldb);
        k_agg<<<ROWS / 4, 256, 0, stream>>>(
            (const float4*)hbuf, (const float4*)lsb, (const float4*)ldb, rowptr_p, csr_src, deg,
            (const float4*)(bg + (size_t)l * HID), (float4*)x0);
    }

    k_gi_gemm<<<KSPLIT, 256, 0, stream>>>(x0, W_ih, gip);
    k_gi_reduce1<<<dim3(GOSZ / 256, 10), 256, 0, stream>>>(gip, gip2);
    k_gi_reduce2<<<GOSZ / 256, 256, 0, stream>>>(gip2, b_ih, gib);
    k_gru<<<1, 256, 0, stream>>>(gib, W_hh, b_hh, hTb);
    k_final<<<(NB * NNODE + 255) / 256, 256, 0, stream>>>(hTb, W_fc, b_fc, out);
}

// Round 11
// 630.263 us; speedup vs baseline: 1.2885x; 1.1100x over previous
//
#include <hip/hip_runtime.h>
#include <math.h>

#define NB 4
#define TT 16
#define NNODE 1000
#define FIN 8
#define EE 8000
#define EP 9000          // E + N self loops
#define EPAD 16384       // max padded edges (pad rows to mult of 8)
#define HID 64
#define HEADS 4
#define NL 5
#define GG (NB*TT)       // 64 graphs
#define ROWS (GG*NNODE)  // 64000
#define HCOL (HEADS*HID) // 256
#define KGI (NNODE*HID)  // 64000
#define GOUT 192         // 3*HID
#define GIK 128          // K-slice per gi-gemm block
#define KSPLIT (KGI/GIK) // 500 partial slabs
#define GOSZ (GG*GOUT)   // 12288

// ---------------- edge prep ----------------
__global__ void k_build_edges(const int* __restrict__ eidx, int* __restrict__ src_e,
                              int* __restrict__ dst_e, int* __restrict__ deg, int* __restrict__ fill) {
    int i = blockIdx.x * blockDim.x + threadIdx.x;
    if (i < EP) {
        int s, d;
        if (i < EE) { s = eidx[i]; d = eidx[EE + i]; }
        else { s = i - EE; d = i - EE; }
        src_e[i] = s; dst_e[i] = d;
    }
    if (i < NNODE) { deg[i] = 0; fill[i] = 0; }
}

__global__ void k_csr_count(const int* __restrict__ dst_e, int* __restrict__ deg) {
    int i = blockIdx.x * blockDim.x + threadIdx.x;
    if (i < EP) atomicAdd(&deg[dst_e[i]], 1);
}

// parallel inclusive scan of PADDED degrees (pad to multiple of 8)
__global__ __launch_bounds__(256) void k_csr_scan(const int* __restrict__ deg, int* __restrict__ rowptr_p) {
    __shared__ int s[1024];
    int tid = threadIdx.x;
    for (int i = tid; i < 1024; i += 256) s[i] = (i < NNODE) ? ((deg[i] + 7) & ~7) : 0;
    __syncthreads();
    for (int off = 1; off < 1024; off <<= 1) {
        int t[4];
        #pragma unroll
        for (int q = 0; q < 4; q++) { int i = tid + 256 * q; t[q] = (i >= off) ? s[i - off] : 0; }
        __syncthreads();
        #pragma unroll
        for (int q = 0; q < 4; q++) { int i = tid + 256 * q; s[i] += t[q]; }
        __syncthreads();
    }
    for (int i = tid; i < NNODE; i += 256) rowptr_p[i + 1] = s[i];
    if (tid == 0) rowptr_p[0] = 0;
}

__global__ void k_csr_fill(const int* __restrict__ src_e, const int* __restrict__ dst_e,
                           const int* __restrict__ rowptr_p, int* __restrict__ fill,
                           int* __restrict__ csr_src) {
    int i = blockIdx.x * blockDim.x + threadIdx.x;
    if (i < EP) {
        int d = dst_e[i];
        int pos = atomicAdd(&fill[d], 1);
        csr_src[rowptr_p[d] + pos] = src_e[i];
    }
}

// fill pad slots with dummy self-edges (they get alpha = 0 in the fused agg)
__global__ void k_pad_fill(const int* __restrict__ rowptr_p, const int* __restrict__ deg,
                           int* __restrict__ csr_src) {
    int n = blockIdx.x * blockDim.x + threadIdx.x;
    if (n >= NNODE) return;
    int rs = rowptr_p[n], re = rowptr_p[n + 1];
    for (int j = rs + deg[n]; j < re; j++) csr_src[j] = n;
}

// ---------------- input projection (float4 over columns) ----------------
__global__ void k_input_fc(const float* __restrict__ xseq, const float4* __restrict__ Win4,
                           const float4* __restrict__ b_in4, float4* __restrict__ x0) {
    int idx = blockIdx.x * 256 + threadIdx.x;   // ROWS*16 threads
    int r = idx >> 4, c4 = idx & 15;
    float4 acc = b_in4[c4];
    #pragma unroll
    for (int k = 0; k < FIN; k++) {
        float xv = xseq[r * FIN + k];
        float4 w = Win4[k * 16 + c4];
        acc.x += xv * w.x; acc.y += xv * w.y; acc.z += xv * w.z; acc.w += xv * w.w;
    }
    x0[idx] = acc;
}

// ---------------- GAT: h = x @ W. 128 rows x 128 cols (2 heads) per block, 8x8/thread.
// x staged in LDS (34 KB); W read per-k via global (L1/L2-resident). ls/ld fused.
__global__ __launch_bounds__(256) void k_gat_h(const float4* __restrict__ x4, const float* __restrict__ W,
                                               const float* __restrict__ asrc, const float* __restrict__ adst,
                                               float* __restrict__ h, float* __restrict__ ls, float* __restrict__ ld) {
    __shared__ float xs[64 * 132];    // [k][row], pitch 132
    int tid = threadIdx.x;
    int r0 = blockIdx.x * 128;
    int hb = blockIdx.y;              // 0..1 -> heads 2*hb, 2*hb+1
    int c0 = hb * 128;
    int rg = tid >> 4;                // 0..15, 8 rows each
    int cg = tid & 15;                // 0..15, 8 cols each
    {
        int row = tid & 127;
        int kq0 = tid >> 7;           // 0..1
        #pragma unroll
        for (int it = 0; it < 8; it++) {
            int kq = kq0 + 2 * it;    // 0..15
            float4 v = x4[(size_t)(r0 + row) * 16 + kq];
            int k = kq * 4;
            xs[(k + 0) * 132 + row] = v.x;
            xs[(k + 1) * 132 + row] = v.y;
            xs[(k + 2) * 132 + row] = v.z;
            xs[(k + 3) * 132 + row] = v.w;
        }
    }
    __syncthreads();
    const float* wp = W + c0 + cg * 8;
    float acc[8][8];
    #pragma unroll
    for (int i = 0; i < 8; i++)
        #pragma unroll
        for (int j = 0; j < 8; j++) acc[i][j] = 0.f;
    #pragma unroll 4
    for (int k = 0; k < 64; k++) {
        float4 w0 = *reinterpret_cast<const float4*>(&wp[(size_t)k * HCOL]);
        float4 w1 = *reinterpret_cast<const float4*>(&wp[(size_t)k * HCOL + 4]);
        float4 xv0 = *reinterpret_cast<const float4*>(&xs[k * 132 + rg * 8]);
        float4 xv1 = *reinterpret_cast<const float4*>(&xs[k * 132 + rg * 8 + 4]);
        float xr[8] = {xv0.x, xv0.y, xv0.z, xv0.w, xv1.x, xv1.y, xv1.z, xv1.w};
        #pragma unroll
        for (int i = 0; i < 8; i++) {
            acc[i][0] += xr[i] * w0.x; acc[i][1] += xr[i] * w0.y;
            acc[i][2] += xr[i] * w0.z; acc[i][3] += xr[i] * w0.w;
            acc[i][4] += xr[i] * w1.x; acc[i][5] += xr[i] * w1.y;
            acc[i][6] += xr[i] * w1.z; acc[i][7] += xr[i] * w1.w;
        }
    }
    int head = 2 * hb + (cg >> 3);
    int ccg = cg & 7;
    float4 av0 = *reinterpret_cast<const float4*>(&asrc[head * 64 + ccg * 8]);
    float4 av1 = *reinterpret_cast<const float4*>(&asrc[head * 64 + ccg * 8 + 4]);
    float4 dv0 = *reinterpret_cast<const float4*>(&adst[head * 64 + ccg * 8]);
    float4 dv1 = *reinterpret_cast<const float4*>(&adst[head * 64 + ccg * 8 + 4]);
    #pragma unroll
    for (int i = 0; i < 8; i++) {
        int row = r0 + rg * 8 + i;
        *reinterpret_cast<float4*>(&h[(size_t)row * HCOL + c0 + cg * 8]) =
            make_float4(acc[i][0], acc[i][1], acc[i][2], acc[i][3]);
        *reinterpret_cast<float4*>(&h[(size_t)row * HCOL + c0 + cg * 8 + 4]) =
            make_float4(acc[i][4], acc[i][5], acc[i][6], acc[i][7]);
        float ps = acc[i][0] * av0.x + acc[i][1] * av0.y + acc[i][2] * av0.z + acc[i][3] * av0.w
                 + acc[i][4] * av1.x + acc[i][5] * av1.y + acc[i][6] * av1.z + acc[i][7] * av1.w;
        float pd = acc[i][0] * dv0.x + acc[i][1] * dv0.y + acc[i][2] * dv0.z + acc[i][3] * dv0.w
                 + acc[i][4] * dv1.x + acc[i][5] * dv1.y + acc[i][6] * dv1.z + acc[i][7] * dv1.w;
        #pragma unroll
        for (int m = 1; m < 8; m <<= 1) {
            ps += __shfl_xor(ps, m, 64);
            pd += __shfl_xor(pd, m, 64);
        }
        if (ccg == 0) {
            ls[(size_t)row * HEADS + head] = ps;
            ld[(size_t)row * HEADS + head] = pd;
        }
    }
}

// ---------------- fused softmax + aggregate: one wave per 4 nodes, 16-lane-group softmax ----------------
// LDS layout (wave-private, no barriers): s_e head stride 68 (banks {0,4,8,12} across heads -> conflict-free)
__global__ __launch_bounds__(256) void k_agg(const float4* __restrict__ h4, const float4* __restrict__ ls4,
                                             const float4* __restrict__ ld4, const int* __restrict__ rowptr_p,
                                             const int* __restrict__ csr_src, const int* __restrict__ deg,
                                             const float4* __restrict__ bg4, float4* __restrict__ xout4) {
    __shared__ float s_e[4][4][4 * 68];   // [wave][node][head*68 + j], j < 64
    __shared__ int   s_src[4][4][64];     // [wave][node][j]
    __shared__ float s_den[4][4][4];      // [wave][node][head]
    int b = blockIdx.x;                   // 0..3999
    int xcd = b & 7, s = b >> 3;          // XCD round-robin
    int tid = threadIdx.x;
    int wid = tid >> 6, lane = tid & 63;
    int w = s * 4 + wid;                  // 0..1999 per XCD
    int g = xcd + 8 * (w / 250);
    int n0 = (w % 250) * 4;
    int nsub = lane >> 4;                 // node slot 0..3 (softmax phase)
    int j0 = lane & 15;                   // edge slot within group
    int n_s = n0 + nsub;
    int rs = rowptr_p[n_s];
    int dgp = rowptr_p[n_s + 1] - rs;
    int dg = deg[n_s];
    int dg16 = (dgp + 15) & ~15;
    if (dg16 > 64) dg16 = 64;             // safety clamp (unreachable at E=8000)
    float4 ldv = ld4[(size_t)g * NNODE + n_s];
    const float4* lsg = ls4 + (size_t)g * NNODE;

    // --- pass A: logits + running max (per 16-lane group) ---
    float4 mx = make_float4(-1e30f, -1e30f, -1e30f, -1e30f);
    for (int base = 0; base < dg16; base += 16) {
        int j = base + j0;
        int sv = n_s;
        if (j < dgp) sv = csr_src[rs + j];
        s_src[wid][nsub][j] = sv;
        float4 lo = make_float4(-1e30f, -1e30f, -1e30f, -1e30f);
        if (j < dg) {
            float4 t = lsg[sv];
            t.x += ldv.x; t.y += ldv.y; t.z += ldv.z; t.w += ldv.w;
            t.x = fmaxf(t.x, 0.2f * t.x); t.y = fmaxf(t.y, 0.2f * t.y);
            t.z = fmaxf(t.z, 0.2f * t.z); t.w = fmaxf(t.w, 0.2f * t.w);
            lo = t;
            mx.x = fmaxf(mx.x, lo.x); mx.y = fmaxf(mx.y, lo.y);
            mx.z = fmaxf(mx.z, lo.z); mx.w = fmaxf(mx.w, lo.w);
        }
        s_e[wid][nsub][0 * 68 + j] = lo.x;
        s_e[wid][nsub][1 * 68 + j] = lo.y;
        s_e[wid][nsub][2 * 68 + j] = lo.z;
        s_e[wid][nsub][3 * 68 + j] = lo.w;
    }
    #pragma unroll
    for (int o = 1; o < 16; o <<= 1) {    // 16-wide butterfly (stays within group)
        mx.x = fmaxf(mx.x, __shfl_xor(mx.x, o, 64));
        mx.y = fmaxf(mx.y, __shfl_xor(mx.y, o, 64));
        mx.z = fmaxf(mx.z, __shfl_xor(mx.z, o, 64));
        mx.w = fmaxf(mx.w, __shfl_xor(mx.w, o, 64));
    }
    // --- pass B: exp + denominator; store unnormalized e ---
    float4 den = make_float4(0.f, 0.f, 0.f, 0.f);
    for (int base = 0; base < dg16; base += 16) {
        int j = base + j0;
        float4 e = make_float4(0.f, 0.f, 0.f, 0.f);
        if (j < dg) {
            e.x = expf(s_e[wid][nsub][0 * 68 + j] - mx.x);
            e.y = expf(s_e[wid][nsub][1 * 68 + j] - mx.y);
            e.z = expf(s_e[wid][nsub][2 * 68 + j] - mx.z);
            e.w = expf(s_e[wid][nsub][3 * 68 + j] - mx.w);
        }
        den.x += e.x; den.y += e.y; den.z += e.z; den.w += e.w;
        s_e[wid][nsub][0 * 68 + j] = e.x;
        s_e[wid][nsub][1 * 68 + j] = e.y;
        s_e[wid][nsub][2 * 68 + j] = e.z;
        s_e[wid][nsub][3 * 68 + j] = e.w;
    }
    #pragma unroll
    for (int o = 1; o < 16; o <<= 1) {
        den.x += __shfl_xor(den.x, o, 64);
        den.y += __shfl_xor(den.y, o, 64);
        den.z += __shfl_xor(den.z, o, 64);
        den.w += __shfl_xor(den.w, o, 64);
    }
    if (j0 == 0) {
        s_den[wid][nsub][0] = den.x;
        s_den[wid][nsub][1] = den.y;
        s_den[wid][nsub][2] = den.z;
        s_den[wid][nsub][3] = den.w;
    }

    // --- gather phase: lane = head*16 + c4; wave loops over its 4 nodes ---
    int head = lane >> 4, c4 = lane & 15;
    const float4* hg = h4 + (size_t)g * NNODE * 64 + lane;
    float4 bb = bg4[c4];
    #pragma unroll
    for (int nn = 0; nn < 4; nn++) {
        int n = n0 + nn;
        int dgc = __shfl(dg16, nn * 16, 64);
        float inv = 1.f / (s_den[wid][nn][head] + 1e-16f);
        const float* ep = &s_e[wid][nn][head * 68];
        const int* sp = &s_src[wid][nn][0];
        float4 acc = make_float4(0.f, 0.f, 0.f, 0.f);
        for (int q = 0; q < dgc; q += 16) {
            int sj[16]; float av[16];
            #pragma unroll
            for (int u = 0; u < 16; u++) {
                sj[u] = sp[q + u];
                av[u] = ep[q + u];
            }
            float4 hv[16];
            #pragma unroll
            for (int u = 0; u < 16; u++) hv[u] = hg[(size_t)sj[u] * 64];
            #pragma unroll
            for (int u = 0; u < 16; u++) {
                acc.x += av[u] * hv[u].x;
                acc.y += av[u] * hv[u].y;
                acc.z += av[u] * hv[u].z;
                acc.w += av[u] * hv[u].w;
            }
        }
        acc.x *= inv; acc.y *= inv; acc.z *= inv; acc.w *= inv;   // per-head normalize
        #pragma unroll
        for (int o = 16; o < 64; o <<= 1) {
            acc.x += __shfl_xor(acc.x, o, 64);
            acc.y += __shfl_xor(acc.y, o, 64);
            acc.z += __shfl_xor(acc.z, o, 64);
            acc.w += __shfl_xor(acc.w, o, 64);
        }
        if (head == 0) {
            float4 r;
            r.x = acc.x * 0.25f + bb.x;
            r.y = acc.y * 0.25f + bb.y;
            r.z = acc.z * 0.25f + bb.z;
            r.w = acc.w * 0.25f + bb.w;
            r.x = r.x > 0.f ? r.x : expm1f(r.x);
            r.y = r.y > 0.f ? r.y : expm1f(r.y);
            r.z = r.z > 0.f ? r.z : expm1f(r.z);
            r.w = r.w > 0.f ? r.w : expm1f(r.w);
            xout4[((size_t)g * NNODE + n) * 16 + c4] = r;
        }
    }
}

// ---------------- GRU input GEMM: 500 K-slices, full 64x192 tile/block, no atomics ----------------
__global__ __launch_bounds__(256) void k_gi_gemm(const float* __restrict__ x, const float* __restrict__ W_ih,
                                                 float* __restrict__ gip) {
    __shared__ float xs[32 * 68];    // [kk][row], pitch 68
    __shared__ float ws[32 * 196];   // [kk][col 0..191], pitch 196
    int k0 = blockIdx.x * GIK;
    int tid = threadIdx.x;
    int lane = tid & 63;
    int wv = tid >> 6;
    int tx = tid & 15, ty = tid >> 4;
    float4 accs[4][3];
    #pragma unroll
    for (int i = 0; i < 4; i++)
        #pragma unroll
        for (int j = 0; j < 3; j++) accs[i][j] = make_float4(0.f, 0.f, 0.f, 0.f);

    for (int kt = 0; kt < GIK / 32; kt++) {
        int kb = k0 + kt * 32;
        #pragma unroll
        for (int it = 0; it < 2; it++) {
            int kq = wv + 4 * it;
            float4 v = *reinterpret_cast<const float4*>(&x[(size_t)lane * KGI + kb + kq * 4]);
            int k = kq * 4;
            xs[(k + 0) * 68 + lane] = v.x;
            xs[(k + 1) * 68 + lane] = v.y;
            xs[(k + 2) * 68 + lane] = v.z;
            xs[(k + 3) * 68 + lane] = v.w;
        }
        #pragma unroll
        for (int cg = 0; cg < 3; cg++) {
            #pragma unroll
            for (int it = 0; it < 2; it++) {
                int kq = wv + 4 * it;
                int c = cg * 64 + lane;
                float4 v = *reinterpret_cast<const float4*>(&W_ih[(size_t)c * KGI + kb + kq * 4]);
                int k = kq * 4;
                ws[(k + 0) * 196 + c] = v.x;
                ws[(k + 1) * 196 + c] = v.y;
                ws[(k + 2) * 196 + c] = v.z;
                ws[(k + 3) * 196 + c] = v.w;
            }
        }
        __syncthreads();
        for (int kk = 0; kk < 32; kk++) {
            float4 xv = *reinterpret_cast<const float4*>(&xs[kk * 68 + ty * 4]);
            float4 w0 = *reinterpret_cast<const float4*>(&ws[kk * 196 + tx * 4]);
            float4 w1 = *reinterpret_cast<const float4*>(&ws[kk * 196 + 64 + tx * 4]);
            float4 w2 = *reinterpret_cast<const float4*>(&ws[kk * 196 + 128 + tx * 4]);
            #pragma unroll
            for (int i = 0; i < 4; i++) {
                float xi = (i == 0) ? xv.x : (i == 1) ? xv.y : (i == 2) ? xv.z : xv.w;
                accs[i][0].x += xi * w0.x; accs[i][0].y += xi * w0.y; accs[i][0].z += xi * w0.z; accs[i][0].w += xi * w0.w;
                accs[i][1].x += xi * w1.x; accs[i][1].y += xi * w1.y; accs[i][1].z += xi * w1.z; accs[i][1].w += xi * w1.w;
                accs[i][2].x += xi * w2.x; accs[i][2].y += xi * w2.y; accs[i][2].z += xi * w2.z; accs[i][2].w += xi * w2.w;
            }
        }
        __syncthreads();
    }
    float* out = gip + (size_t)blockIdx.x * GOSZ;
    #pragma unroll
    for (int i = 0; i < 4; i++)
        #pragma unroll
        for (int j = 0; j < 3; j++)
            *reinterpret_cast<float4*>(&out[(ty * 4 + i) * GOUT + j * 64 + tx * 4]) = accs[i][j];
}

__global__ void k_gi_reduce1(const float* __restrict__ gip, float* __restrict__ gip2) {
    int idx = blockIdx.x * 256 + threadIdx.x;     // 0..GOSZ-1
    const float* p = gip + (size_t)blockIdx.y * 50 * GOSZ + idx;
    float a = 0.f;
    #pragma unroll 5
    for (int s = 0; s < 50; s++) a += p[(size_t)s * GOSZ];
    gip2[blockIdx.y * GOSZ + idx] = a;
}

__global__ void k_gi_reduce2(const float* __restrict__ gip2, const float* __restrict__ b_ih,
                             float* __restrict__ gi) {
    int idx = blockIdx.x * 256 + threadIdx.x;
    float a = b_ih[idx % GOUT];
    #pragma unroll
    for (int y = 0; y < 10; y++) a += gip2[(size_t)y * GOSZ + idx];
    gi[idx] = a;
}

// ---------------- GRU scan (single block) ----------------
__global__ __launch_bounds__(256) void k_gru(const float* __restrict__ gi, const float* __restrict__ W_hh,
                                             const float* __restrict__ b_hh, float* __restrict__ hT) {
    __shared__ float Wt[64 * 192];   // [c][j] transposed
    __shared__ float hs[4][64];
    __shared__ float gh[4][192];
    int tid = threadIdx.x;
    for (int idx = tid; idx < 192 * 64; idx += 256) {
        int j = idx >> 6, c = idx & 63;
        Wt[c * 192 + j] = W_hh[idx];
    }
    int b_ = tid >> 6, c_ = tid & 63;
    hs[b_][c_] = 0.f;
    __syncthreads();
    for (int t = 0; t < TT; t++) {
        #pragma unroll
        for (int q = 0; q < 3; q++) {
            int p = tid + 256 * q;
            int bb = p / GOUT, j = p % GOUT;
            float a = b_hh[j];
            for (int c = 0; c < 64; c++) a += hs[bb][c] * Wt[c * 192 + j];
            gh[bb][j] = a;
        }
        __syncthreads();
        int row = (b_ * TT + t) * GOUT;
        float ir = gi[row + c_], iz = gi[row + 64 + c_], in_ = gi[row + 128 + c_];
        float r = 1.f / (1.f + expf(-(ir + gh[b_][c_])));
        float z = 1.f / (1.f + expf(-(iz + gh[b_][64 + c_])));
        float nv = tanhf(in_ + r * gh[b_][128 + c_]);
        float hn = (1.f - z) * nv + z * hs[b_][c_];
        hs[b_][c_] = hn;
        __syncthreads();
    }
    hT[tid] = hs[b_][c_];
}

// ---------------- final FC ----------------
__global__ void k_final(const float* __restrict__ hT, const float* __restrict__ W_fc,
                        const float* __restrict__ b_fc, float* __restrict__ out) {
    int idx = blockIdx.x * 256 + threadIdx.x;
    if (idx >= NB * NNODE) return;
    int b = idx / NNODE, n = idx % NNODE;
    float acc = b_fc[n];
    #pragma unroll
    for (int c = 0; c < HID; c++) acc += hT[b * HID + c] * W_fc[c * NNODE + n];
    out[idx] = acc;
}

extern "C" void kernel_launch(void* const* d_in, const int* in_sizes, int n_in,
                              void* d_out, int out_size, void* d_ws, size_t ws_size,
                              hipStream_t stream) {
    const float* x_seq  = (const float*)d_in[0];
    const int*   eidx   = (const int*)  d_in[1];
    // d_in[2] edge_weight: unused by GATConv
    const float* W_in   = (const float*)d_in[3];
    const float* b_in   = (const float*)d_in[4];
    const float* Wg     = (const float*)d_in[5];
    const float* a_src  = (const float*)d_in[6];
    const float* a_dst  = (const float*)d_in[7];
    const float* bg     = (const float*)d_in[8];
    const float* W_ih   = (const float*)d_in[9];
    const float* W_hh   = (const float*)d_in[10];
    const float* b_ih   = (const float*)d_in[11];
    const float* b_hh   = (const float*)d_in[12];
    const float* W_fc   = (const float*)d_in[13];
    const float* b_fc   = (const float*)d_in[14];
    float* out = (float*)d_out;

    float* wsf = (float*)d_ws;
    size_t off = 0;
    float* x0     = wsf + off; off += (size_t)ROWS * HID;       // 4,096,000
    float* hbuf   = wsf + off; off += (size_t)ROWS * HCOL;      // 16,384,000
    float* lsb    = wsf + off; off += (size_t)ROWS * HEADS;     // 256,000
    float* ldb    = wsf + off; off += (size_t)ROWS * HEADS;     // 256,000
    float* gib    = wsf + off; off += GOSZ;                     // 12,288
    float* hTb    = wsf + off; off += 256;
    int* ib = (int*)(wsf + off);
    int* src_e    = ib;          ib += EP;
    int* dst_e    = ib;          ib += EP;
    int* rowptr_p = ib;          ib += NNODE + 1;
    int* csr_src  = ib;          ib += EPAD;
    int* deg      = ib;          ib += NNODE;
    int* fill     = ib;          ib += NNODE;

    // gi partials alias hbuf (dead after last k_agg): (500+10)*12288 floats << 16.38M
    float* gip  = hbuf;
    float* gip2 = hbuf + (size_t)KSPLIT * GOSZ;

    k_build_edges<<<(EP + 255) / 256, 256, 0, stream>>>(eidx, src_e, dst_e, deg, fill);
    k_csr_count<<<(EP + 255) / 256, 256, 0, stream>>>(dst_e, deg);
    k_csr_scan<<<1, 256, 0, stream>>>(deg, rowptr_p);
    k_csr_fill<<<(EP + 255) / 256, 256, 0, stream>>>(src_e, dst_e, rowptr_p, fill, csr_src);
    k_pad_fill<<<(NNODE + 255) / 256, 256, 0, stream>>>(rowptr_p, deg, csr_src);

    k_input_fc<<<ROWS * 16 / 256, 256, 0, stream>>>(x_seq, (const float4*)W_in, (const float4*)b_in,
                                                    (float4*)x0);

    for (int l = 0; l < NL; l++) {
        k_gat_h<<<dim3(ROWS / 128, 2), 256, 0, stream>>>(
            (const float4*)x0, Wg + (size_t)l * HID * HCOL,
            a_src + (size_t)l * HEADS * HID, a_dst + (size_t)l * HEADS * HID, hbuf, lsb, ldb);
        k_agg<<<ROWS / 16, 256, 0, stream>>>(
            (const float4*)hbuf, (const float4*)lsb, (const float4*)ldb, rowptr_p, csr_src, deg,
            (const float4*)(bg + (size_t)l * HID), (float4*)x0);
    }

    k_gi_gemm<<<KSPLIT, 256, 0, stream>>>(x0, W_ih, gip);
    k_gi_reduce1<<<dim3(GOSZ / 256, 10), 256, 0, stream>>>(gip, gip2);
    k_gi_reduce2<<<GOSZ / 256, 256, 0, stream>>>(gip2, b_ih, gib);
    k_gru<<<1, 256, 0, stream>>>(gib, W_hh, b_hh, hTb);
    k_final<<<(NB * NNODE + 255) / 256, 256, 0, stream>>>(hTb, W_fc, b_fc, out);
}

// Round 12
// 605.599 us; speedup vs baseline: 1.3410x; 1.0407x over previous
//
#include <hip/hip_runtime.h>
#include <math.h>

#define NB 4
#define TT 16
#define NNODE 1000
#define FIN 8
#define EE 8000
#define EP 9000          // E + N self loops
#define EPAD 16384       // max padded edges (pad rows to mult of 8)
#define HID 64
#define HEADS 4
#define NL 5
#define GG (NB*TT)       // 64 graphs
#define ROWS (GG*NNODE)  // 64000
#define HCOL (HEADS*HID) // 256
#define KGI (NNODE*HID)  // 64000
#define GOUT 192         // 3*HID
#define GIK 128          // K-slice per gi-gemm block
#define KSPLIT (KGI/GIK) // 500 partial slabs
#define GOSZ (GG*GOUT)   // 12288

// ---------------- edge prep ----------------
__global__ void k_build_edges(const int* __restrict__ eidx, int* __restrict__ src_e,
                              int* __restrict__ dst_e, int* __restrict__ deg, int* __restrict__ fill) {
    int i = blockIdx.x * blockDim.x + threadIdx.x;
    if (i < EP) {
        int s, d;
        if (i < EE) { s = eidx[i]; d = eidx[EE + i]; }
        else { s = i - EE; d = i - EE; }
        src_e[i] = s; dst_e[i] = d;
    }
    if (i < NNODE) { deg[i] = 0; fill[i] = 0; }
}

__global__ void k_csr_count(const int* __restrict__ dst_e, int* __restrict__ deg) {
    int i = blockIdx.x * blockDim.x + threadIdx.x;
    if (i < EP) atomicAdd(&deg[dst_e[i]], 1);
}

// parallel inclusive scan of PADDED degrees (pad to multiple of 8)
__global__ __launch_bounds__(256) void k_csr_scan(const int* __restrict__ deg, int* __restrict__ rowptr_p) {
    __shared__ int s[1024];
    int tid = threadIdx.x;
    for (int i = tid; i < 1024; i += 256) s[i] = (i < NNODE) ? ((deg[i] + 7) & ~7) : 0;
    __syncthreads();
    for (int off = 1; off < 1024; off <<= 1) {
        int t[4];
        #pragma unroll
        for (int q = 0; q < 4; q++) { int i = tid + 256 * q; t[q] = (i >= off) ? s[i - off] : 0; }
        __syncthreads();
        #pragma unroll
        for (int q = 0; q < 4; q++) { int i = tid + 256 * q; s[i] += t[q]; }
        __syncthreads();
    }
    for (int i = tid; i < NNODE; i += 256) rowptr_p[i + 1] = s[i];
    if (tid == 0) rowptr_p[0] = 0;
}

__global__ void k_csr_fill(const int* __restrict__ src_e, const int* __restrict__ dst_e,
                           const int* __restrict__ rowptr_p, int* __restrict__ fill,
                           int* __restrict__ csr_src) {
    int i = blockIdx.x * blockDim.x + threadIdx.x;
    if (i < EP) {
        int d = dst_e[i];
        int pos = atomicAdd(&fill[d], 1);
        csr_src[rowptr_p[d] + pos] = src_e[i];
    }
}

// fill pad slots with dummy self-edges (they get alpha = 0 in the fused agg)
__global__ void k_pad_fill(const int* __restrict__ rowptr_p, const int* __restrict__ deg,
                           int* __restrict__ csr_src) {
    int n = blockIdx.x * blockDim.x + threadIdx.x;
    if (n >= NNODE) return;
    int rs = rowptr_p[n], re = rowptr_p[n + 1];
    for (int j = rs + deg[n]; j < re; j++) csr_src[j] = n;
}

// ---------------- input projection (float4 over columns) ----------------
__global__ void k_input_fc(const float* __restrict__ xseq, const float4* __restrict__ Win4,
                           const float4* __restrict__ b_in4, float4* __restrict__ x0) {
    int idx = blockIdx.x * 256 + threadIdx.x;   // ROWS*16 threads
    int r = idx >> 4, c4 = idx & 15;
    float4 acc = b_in4[c4];
    #pragma unroll
    for (int k = 0; k < FIN; k++) {
        float xv = xseq[r * FIN + k];
        float4 w = Win4[k * 16 + c4];
        acc.x += xv * w.x; acc.y += xv * w.y; acc.z += xv * w.z; acc.w += xv * w.w;
    }
    x0[idx] = acc;
}

// ---------------- GAT: h = x @ W. 128 rows x 128 cols (2 heads) per block, 8x8/thread.
// x staged in LDS (34 KB); W read per-k via global (L1/L2-resident). ls/ld fused.
__global__ __launch_bounds__(256) void k_gat_h(const float4* __restrict__ x4, const float* __restrict__ W,
                                               const float* __restrict__ asrc, const float* __restrict__ adst,
                                               float* __restrict__ h, float* __restrict__ ls, float* __restrict__ ld) {
    __shared__ float xs[64 * 132];    // [k][row], pitch 132
    int tid = threadIdx.x;
    int r0 = blockIdx.x * 128;
    int hb = blockIdx.y;              // 0..1 -> heads 2*hb, 2*hb+1
    int c0 = hb * 128;
    int rg = tid >> 4;                // 0..15, 8 rows each
    int cg = tid & 15;                // 0..15, 8 cols each
    {
        int row = tid & 127;
        int kq0 = tid >> 7;           // 0..1
        #pragma unroll
        for (int it = 0; it < 8; it++) {
            int kq = kq0 + 2 * it;    // 0..15
            float4 v = x4[(size_t)(r0 + row) * 16 + kq];
            int k = kq * 4;
            xs[(k + 0) * 132 + row] = v.x;
            xs[(k + 1) * 132 + row] = v.y;
            xs[(k + 2) * 132 + row] = v.z;
            xs[(k + 3) * 132 + row] = v.w;
        }
    }
    __syncthreads();
    const float* wp = W + c0 + cg * 8;
    float acc[8][8];
    #pragma unroll
    for (int i = 0; i < 8; i++)
        #pragma unroll
        for (int j = 0; j < 8; j++) acc[i][j] = 0.f;
    #pragma unroll 4
    for (int k = 0; k < 64; k++) {
        float4 w0 = *reinterpret_cast<const float4*>(&wp[(size_t)k * HCOL]);
        float4 w1 = *reinterpret_cast<const float4*>(&wp[(size_t)k * HCOL + 4]);
        float4 xv0 = *reinterpret_cast<const float4*>(&xs[k * 132 + rg * 8]);
        float4 xv1 = *reinterpret_cast<const float4*>(&xs[k * 132 + rg * 8 + 4]);
        float xr[8] = {xv0.x, xv0.y, xv0.z, xv0.w, xv1.x, xv1.y, xv1.z, xv1.w};
        #pragma unroll
        for (int i = 0; i < 8; i++) {
            acc[i][0] += xr[i] * w0.x; acc[i][1] += xr[i] * w0.y;
            acc[i][2] += xr[i] * w0.z; acc[i][3] += xr[i] * w0.w;
            acc[i][4] += xr[i] * w1.x; acc[i][5] += xr[i] * w1.y;
            acc[i][6] += xr[i] * w1.z; acc[i][7] += xr[i] * w1.w;
        }
    }
    int head = 2 * hb + (cg >> 3);
    int ccg = cg & 7;
    float4 av0 = *reinterpret_cast<const float4*>(&asrc[head * 64 + ccg * 8]);
    float4 av1 = *reinterpret_cast<const float4*>(&asrc[head * 64 + ccg * 8 + 4]);
    float4 dv0 = *reinterpret_cast<const float4*>(&adst[head * 64 + ccg * 8]);
    float4 dv1 = *reinterpret_cast<const float4*>(&adst[head * 64 + ccg * 8 + 4]);
    #pragma unroll
    for (int i = 0; i < 8; i++) {
        int row = r0 + rg * 8 + i;
        *reinterpret_cast<float4*>(&h[(size_t)row * HCOL + c0 + cg * 8]) =
            make_float4(acc[i][0], acc[i][1], acc[i][2], acc[i][3]);
        *reinterpret_cast<float4*>(&h[(size_t)row * HCOL + c0 + cg * 8 + 4]) =
            make_float4(acc[i][4], acc[i][5], acc[i][6], acc[i][7]);
        float ps = acc[i][0] * av0.x + acc[i][1] * av0.y + acc[i][2] * av0.z + acc[i][3] * av0.w
                 + acc[i][4] * av1.x + acc[i][5] * av1.y + acc[i][6] * av1.z + acc[i][7] * av1.w;
        float pd = acc[i][0] * dv0.x + acc[i][1] * dv0.y + acc[i][2] * dv0.z + acc[i][3] * dv0.w
                 + acc[i][4] * dv1.x + acc[i][5] * dv1.y + acc[i][6] * dv1.z + acc[i][7] * dv1.w;
        #pragma unroll
        for (int m = 1; m < 8; m <<= 1) {
            ps += __shfl_xor(ps, m, 64);
            pd += __shfl_xor(pd, m, 64);
        }
        if (ccg == 0) {
            ls[(size_t)row * HEADS + head] = ps;
            ld[(size_t)row * HEADS + head] = pd;
        }
    }
}

// ---------------- fused softmax + aggregate: one wave per 4 nodes, 16-lane-group softmax ----------------
// s_e head stride 68 -> heads map to banks {0,4,8,12}: conflict-free broadcast reads.
// Gather: chunk-8 over dgp (pad-to-8), all 4 nodes' gathers issued before any reduce.
__global__ __launch_bounds__(256) void k_agg(const float4* __restrict__ h4, const float4* __restrict__ ls4,
                                             const float4* __restrict__ ld4, const int* __restrict__ rowptr_p,
                                             const int* __restrict__ csr_src, const int* __restrict__ deg,
                                             const float4* __restrict__ bg4, float4* __restrict__ xout4) {
    __shared__ float s_e[4][4][4 * 68];   // [wave][node][head*68 + j], j < 64
    __shared__ int   s_src[4][4][64];     // [wave][node][j]
    __shared__ float s_den[4][4][4];      // [wave][node][head]
    int b = blockIdx.x;                   // 0..3999
    int xcd = b & 7, s = b >> 3;          // XCD round-robin
    int tid = threadIdx.x;
    int wid = tid >> 6, lane = tid & 63;
    int w = s * 4 + wid;                  // 0..1999 per XCD
    int g = xcd + 8 * (w / 250);
    int n0 = (w % 250) * 4;
    int nsub = lane >> 4;                 // node slot 0..3 (softmax phase)
    int j0 = lane & 15;                   // edge slot within group
    int n_s = n0 + nsub;
    int rs = rowptr_p[n_s];
    int dgp = rowptr_p[n_s + 1] - rs;     // multiple of 8
    int dg = deg[n_s];
    int dg16 = (dgp + 15) & ~15;
    if (dg16 > 64) dg16 = 64;             // safety clamp (unreachable at E=8000)
    if (dgp > 64) dgp = 64;
    float4 ldv = ld4[(size_t)g * NNODE + n_s];
    const float4* lsg = ls4 + (size_t)g * NNODE;

    // --- pass A: logits + running max (per 16-lane group) ---
    float4 mx = make_float4(-1e30f, -1e30f, -1e30f, -1e30f);
    for (int base = 0; base < dg16; base += 16) {
        int j = base + j0;
        int sv = n_s;
        if (j < dgp) sv = csr_src[rs + j];
        s_src[wid][nsub][j] = sv;
        float4 lo = make_float4(-1e30f, -1e30f, -1e30f, -1e30f);
        if (j < dg) {
            float4 t = lsg[sv];
            t.x += ldv.x; t.y += ldv.y; t.z += ldv.z; t.w += ldv.w;
            t.x = fmaxf(t.x, 0.2f * t.x); t.y = fmaxf(t.y, 0.2f * t.y);
            t.z = fmaxf(t.z, 0.2f * t.z); t.w = fmaxf(t.w, 0.2f * t.w);
            lo = t;
            mx.x = fmaxf(mx.x, lo.x); mx.y = fmaxf(mx.y, lo.y);
            mx.z = fmaxf(mx.z, lo.z); mx.w = fmaxf(mx.w, lo.w);
        }
        s_e[wid][nsub][0 * 68 + j] = lo.x;
        s_e[wid][nsub][1 * 68 + j] = lo.y;
        s_e[wid][nsub][2 * 68 + j] = lo.z;
        s_e[wid][nsub][3 * 68 + j] = lo.w;
    }
    #pragma unroll
    for (int o = 1; o < 16; o <<= 1) {    // 16-wide butterfly (stays within group)
        mx.x = fmaxf(mx.x, __shfl_xor(mx.x, o, 64));
        mx.y = fmaxf(mx.y, __shfl_xor(mx.y, o, 64));
        mx.z = fmaxf(mx.z, __shfl_xor(mx.z, o, 64));
        mx.w = fmaxf(mx.w, __shfl_xor(mx.w, o, 64));
    }
    // --- pass B: exp + denominator; store unnormalized e (zeros for j >= dg) ---
    float4 den = make_float4(0.f, 0.f, 0.f, 0.f);
    for (int base = 0; base < dg16; base += 16) {
        int j = base + j0;
        float4 e = make_float4(0.f, 0.f, 0.f, 0.f);
        if (j < dg) {
            e.x = expf(s_e[wid][nsub][0 * 68 + j] - mx.x);
            e.y = expf(s_e[wid][nsub][1 * 68 + j] - mx.y);
            e.z = expf(s_e[wid][nsub][2 * 68 + j] - mx.z);
            e.w = expf(s_e[wid][nsub][3 * 68 + j] - mx.w);
        }
        den.x += e.x; den.y += e.y; den.z += e.z; den.w += e.w;
        s_e[wid][nsub][0 * 68 + j] = e.x;
        s_e[wid][nsub][1 * 68 + j] = e.y;
        s_e[wid][nsub][2 * 68 + j] = e.z;
        s_e[wid][nsub][3 * 68 + j] = e.w;
    }
    #pragma unroll
    for (int o = 1; o < 16; o <<= 1) {
        den.x += __shfl_xor(den.x, o, 64);
        den.y += __shfl_xor(den.y, o, 64);
        den.z += __shfl_xor(den.z, o, 64);
        den.w += __shfl_xor(den.w, o, 64);
    }
    if (j0 == 0) {
        s_den[wid][nsub][0] = den.x;
        s_den[wid][nsub][1] = den.y;
        s_den[wid][nsub][2] = den.z;
        s_den[wid][nsub][3] = den.w;
    }

    // --- gather phase: lane = head*16 + c4; all 4 nodes accumulated before any reduce ---
    int head = lane >> 4, c4 = lane & 15;
    const float4* hg = h4 + (size_t)g * NNODE * 64 + lane;
    float4 acc[4];
    #pragma unroll
    for (int nn = 0; nn < 4; nn++) acc[nn] = make_float4(0.f, 0.f, 0.f, 0.f);
    #pragma unroll
    for (int nn = 0; nn < 4; nn++) {
        int dgc = __shfl(dgp, nn * 16, 64);   // node nn's padded degree (mult of 8)
        const float* ep = &s_e[wid][nn][head * 68];
        const int* sp = &s_src[wid][nn][0];
        for (int q = 0; q < dgc; q += 8) {
            int sj[8]; float av[8];
            #pragma unroll
            for (int u = 0; u < 8; u++) {
                sj[u] = sp[q + u];
                av[u] = ep[q + u];
            }
            float4 hv[8];
            #pragma unroll
            for (int u = 0; u < 8; u++) hv[u] = hg[(size_t)sj[u] * 64];
            #pragma unroll
            for (int u = 0; u < 8; u++) {
                acc[nn].x += av[u] * hv[u].x;
                acc[nn].y += av[u] * hv[u].y;
                acc[nn].z += av[u] * hv[u].z;
                acc[nn].w += av[u] * hv[u].w;
            }
        }
    }
    float4 bb = bg4[c4];
    #pragma unroll
    for (int nn = 0; nn < 4; nn++) {
        float inv = 1.f / (s_den[wid][nn][head] + 1e-16f);
        float4 a = acc[nn];
        a.x *= inv; a.y *= inv; a.z *= inv; a.w *= inv;
        #pragma unroll
        for (int o = 16; o < 64; o <<= 1) {
            a.x += __shfl_xor(a.x, o, 64);
            a.y += __shfl_xor(a.y, o, 64);
            a.z += __shfl_xor(a.z, o, 64);
            a.w += __shfl_xor(a.w, o, 64);
        }
        if (head == 0) {
            float4 r;
            r.x = a.x * 0.25f + bb.x;
            r.y = a.y * 0.25f + bb.y;
            r.z = a.z * 0.25f + bb.z;
            r.w = a.w * 0.25f + bb.w;
            r.x = r.x > 0.f ? r.x : expm1f(r.x);
            r.y = r.y > 0.f ? r.y : expm1f(r.y);
            r.z = r.z > 0.f ? r.z : expm1f(r.z);
            r.w = r.w > 0.f ? r.w : expm1f(r.w);
            xout4[((size_t)g * NNODE + n0 + nn) * 16 + c4] = r;
        }
    }
}

// ---------------- GRU input GEMM: 500 K-slices, full 64x192 tile/block, no atomics ----------------
__global__ __launch_bounds__(256) void k_gi_gemm(const float* __restrict__ x, const float* __restrict__ W_ih,
                                                 float* __restrict__ gip) {
    __shared__ float xs[32 * 68];    // [kk][row], pitch 68
    __shared__ float ws[32 * 196];   // [kk][col 0..191], pitch 196
    int k0 = blockIdx.x * GIK;
    int tid = threadIdx.x;
    int lane = tid & 63;
    int wv = tid >> 6;
    int tx = tid & 15, ty = tid >> 4;
    float4 accs[4][3];
    #pragma unroll
    for (int i = 0; i < 4; i++)
        #pragma unroll
        for (int j = 0; j < 3; j++) accs[i][j] = make_float4(0.f, 0.f, 0.f, 0.f);

    for (int kt = 0; kt < GIK / 32; kt++) {
        int kb = k0 + kt * 32;
        #pragma unroll
        for (int it = 0; it < 2; it++) {
            int kq = wv + 4 * it;
            float4 v = *reinterpret_cast<const float4*>(&x[(size_t)lane * KGI + kb + kq * 4]);
            int k = kq * 4;
            xs[(k + 0) * 68 + lane] = v.x;
            xs[(k + 1) * 68 + lane] = v.y;
            xs[(k + 2) * 68 + lane] = v.z;
            xs[(k + 3) * 68 + lane] = v.w;
        }
        #pragma unroll
        for (int cg = 0; cg < 3; cg++) {
            #pragma unroll
            for (int it = 0; it < 2; it++) {
                int kq = wv + 4 * it;
                int c = cg * 64 + lane;
                float4 v = *reinterpret_cast<const float4*>(&W_ih[(size_t)c * KGI + kb + kq * 4]);
                int k = kq * 4;
                ws[(k + 0) * 196 + c] = v.x;
                ws[(k + 1) * 196 + c] = v.y;
                ws[(k + 2) * 196 + c] = v.z;
                ws[(k + 3) * 196 + c] = v.w;
            }
        }
        __syncthreads();
        for (int kk = 0; kk < 32; kk++) {
            float4 xv = *reinterpret_cast<const float4*>(&xs[kk * 68 + ty * 4]);
            float4 w0 = *reinterpret_cast<const float4*>(&ws[kk * 196 + tx * 4]);
            float4 w1 = *reinterpret_cast<const float4*>(&ws[kk * 196 + 64 + tx * 4]);
            float4 w2 = *reinterpret_cast<const float4*>(&ws[kk * 196 + 128 + tx * 4]);
            #pragma unroll
            for (int i = 0; i < 4; i++) {
                float xi = (i == 0) ? xv.x : (i == 1) ? xv.y : (i == 2) ? xv.z : xv.w;
                accs[i][0].x += xi * w0.x; accs[i][0].y += xi * w0.y; accs[i][0].z += xi * w0.z; accs[i][0].w += xi * w0.w;
                accs[i][1].x += xi * w1.x; accs[i][1].y += xi * w1.y; accs[i][1].z += xi * w1.z; accs[i][1].w += xi * w1.w;
                accs[i][2].x += xi * w2.x; accs[i][2].y += xi * w2.y; accs[i][2].z += xi * w2.z; accs[i][2].w += xi * w2.w;
            }
        }
        __syncthreads();
    }
    float* out = gip + (size_t)blockIdx.x * GOSZ;
    #pragma unroll
    for (int i = 0; i < 4; i++)
        #pragma unroll
        for (int j = 0; j < 3; j++)
            *reinterpret_cast<float4*>(&out[(ty * 4 + i) * GOUT + j * 64 + tx * 4]) = accs[i][j];
}

__global__ void k_gi_reduce1(const float* __restrict__ gip, float* __restrict__ gip2) {
    int idx = blockIdx.x * 256 + threadIdx.x;     // 0..GOSZ-1
    const float* p = gip + (size_t)blockIdx.y * 50 * GOSZ + idx;
    float a = 0.f;
    #pragma unroll 5
    for (int s = 0; s < 50; s++) a += p[(size_t)s * GOSZ];
    gip2[blockIdx.y * GOSZ + idx] = a;
}

__global__ void k_gi_reduce2(const float* __restrict__ gip2, const float* __restrict__ b_ih,
                             float* __restrict__ gi) {
    int idx = blockIdx.x * 256 + threadIdx.x;
    float a = b_ih[idx % GOUT];
    #pragma unroll
    for (int y = 0; y < 10; y++) a += gip2[(size_t)y * GOSZ + idx];
    gi[idx] = a;
}

// ---------------- GRU scan (single block) ----------------
__global__ __launch_bounds__(256) void k_gru(const float* __restrict__ gi, const float* __restrict__ W_hh,
                                             const float* __restrict__ b_hh, float* __restrict__ hT) {
    __shared__ float Wt[64 * 192];   // [c][j] transposed
    __shared__ float hs[4][64];
    __shared__ float gh[4][192];
    int tid = threadIdx.x;
    for (int idx = tid; idx < 192 * 64; idx += 256) {
        int j = idx >> 6, c = idx & 63;
        Wt[c * 192 + j] = W_hh[idx];
    }
    int b_ = tid >> 6, c_ = tid & 63;
    hs[b_][c_] = 0.f;
    __syncthreads();
    for (int t = 0; t < TT; t++) {
        #pragma unroll
        for (int q = 0; q < 3; q++) {
            int p = tid + 256 * q;
            int bb = p / GOUT, j = p % GOUT;
            float a = b_hh[j];
            for (int c = 0; c < 64; c++) a += hs[bb][c] * Wt[c * 192 + j];
            gh[bb][j] = a;
        }
        __syncthreads();
        int row = (b_ * TT + t) * GOUT;
        float ir = gi[row + c_], iz = gi[row + 64 + c_], in_ = gi[row + 128 + c_];
        float r = 1.f / (1.f + expf(-(ir + gh[b_][c_])));
        float z = 1.f / (1.f + expf(-(iz + gh[b_][64 + c_])));
        float nv = tanhf(in_ + r * gh[b_][128 + c_]);
        float hn = (1.f - z) * nv + z * hs[b_][c_];
        hs[b_][c_] = hn;
        __syncthreads();
    }
    hT[tid] = hs[b_][c_];
}

// ---------------- final FC ----------------
__global__ void k_final(const float* __restrict__ hT, const float* __restrict__ W_fc,
                        const float* __restrict__ b_fc, float* __restrict__ out) {
    int idx = blockIdx.x * 256 + threadIdx.x;
    if (idx >= NB * NNODE) return;
    int b = idx / NNODE, n = idx % NNODE;
    float acc = b_fc[n];
    #pragma unroll
    for (int c = 0; c < HID; c++) acc += hT[b * HID + c] * W_fc[c * NNODE + n];
    out[idx] = acc;
}

extern "C" void kernel_launch(void* const* d_in, const int* in_sizes, int n_in,
                              void* d_out, int out_size, void* d_ws, size_t ws_size,
                              hipStream_t stream) {
    const float* x_seq  = (const float*)d_in[0];
    const int*   eidx   = (const int*)  d_in[1];
    // d_in[2] edge_weight: unused by GATConv
    const float* W_in   = (const float*)d_in[3];
    const float* b_in   = (const float*)d_in[4];
    const float* Wg     = (const float*)d_in[5];
    const float* a_src  = (const float*)d_in[6];
    const float* a_dst  = (const float*)d_in[7];
    const float* bg     = (const float*)d_in[8];
    const float* W_ih   = (const float*)d_in[9];
    const float* W_hh   = (const float*)d_in[10];
    const float* b_ih   = (const float*)d_in[11];
    const float* b_hh   = (const float*)d_in[12];
    const float* W_fc   = (const float*)d_in[13];
    const float* b_fc   = (const float*)d_in[14];
    float* out = (float*)d_out;

    float* wsf = (float*)d_ws;
    size_t off = 0;
    float* x0     = wsf + off; off += (size_t)ROWS * HID;       // 4,096,000
    float* hbuf   = wsf + off; off += (size_t)ROWS * HCOL;      // 16,384,000
    float* lsb    = wsf + off; off += (size_t)ROWS * HEADS;     // 256,000
    float* ldb    = wsf + off; off += (size_t)ROWS * HEADS;     // 256,000
    float* gib    = wsf + off; off += GOSZ;                     // 12,288
    float* hTb    = wsf + off; off += 256;
    int* ib = (int*)(wsf + off);
    int* src_e    = ib;          ib += EP;
    int* dst_e    = ib;          ib += EP;
    int* rowptr_p = ib;          ib += NNODE + 1;
    int* csr_src  = ib;          ib += EPAD;
    int* deg      = ib;          ib += NNODE;
    int* fill     = ib;          ib += NNODE;

    // gi partials alias hbuf (dead after last k_agg): (500+10)*12288 floats << 16.38M
    float* gip  = hbuf;
    float* gip2 = hbuf + (size_t)KSPLIT * GOSZ;

    k_build_edges<<<(EP + 255) / 256, 256, 0, stream>>>(eidx, src_e, dst_e, deg, fill);
    k_csr_count<<<(EP + 255) / 256, 256, 0, stream>>>(dst_e, deg);
    k_csr_scan<<<1, 256, 0, stream>>>(deg, rowptr_p);
    k_csr_fill<<<(EP + 255) / 256, 256, 0, stream>>>(src_e, dst_e, rowptr_p, fill, csr_src);
    k_pad_fill<<<(NNODE + 255) / 256, 256, 0, stream>>>(rowptr_p, deg, csr_src);

    k_input_fc<<<ROWS * 16 / 256, 256, 0, stream>>>(x_seq, (const float4*)W_in, (const float4*)b_in,
                                                    (float4*)x0);

    for (int l = 0; l < NL; l++) {
        k_gat_h<<<dim3(ROWS / 128, 2), 256, 0, stream>>>(
            (const float4*)x0, Wg + (size_t)l * HID * HCOL,
            a_src + (size_t)l * HEADS * HID, a_dst + (size_t)l * HEADS * HID, hbuf, lsb, ldb);
        k_agg<<<ROWS / 16, 256, 0, stream>>>(
            (const float4*)hbuf, (const float4*)lsb, (const float4*)ldb, rowptr_p, csr_src, deg,
            (const float4*)(bg + (size_t)l * HID), (float4*)x0);
    }

    k_gi_gemm<<<KSPLIT, 256, 0, stream>>>(x0, W_ih, gip);
    k_gi_reduce1<<<dim3(GOSZ / 256, 10), 256, 0, stream>>>(gip, gip2);
    k_gi_reduce2<<<GOSZ / 256, 256, 0, stream>>>(gip2, b_ih, gib);
    k_gru<<<1, 256, 0, stream>>>(gib, W_hh, b_hh, hTb);
    k_final<<<(NB * NNODE + 255) / 256, 256, 0, stream>>>(hTb, W_fc, b_fc, out);
}